// Round 11
// baseline (212.653 us; speedup 1.0000x reference)
//
#include <hip/hip_runtime.h>
#include <hip/hip_bf16.h>

#define NIMG 8
#define NC   80
#define NL   256
#define HWQ  15200
#define TOPK 1000
#define CAP  4096
#define SSORT 2048
#define NPOST 100
#define PERIMG (HWQ * NC)          // 1,216,000
#define TOTAL (NIMG * PERIMG)      // 9,728,000
#define RPB  16                    // rows per score block (8 waves x 2 rows)
#define SBLKR (NIMG * HWQ / RPB)   // 7600
#define PI4  (PERIMG / 4)          // 304,000 float4 per image
#define WPI  (PI4 / 64)            // 4750 waves per image
#define NWAVE (NIMG * WPI)         // 38,000
#define CBLK (TOTAL / 4 / 256)     // 9,500 blocks for count pass

__device__ __forceinline__ unsigned flipKey(float f) {
    unsigned u = __float_as_uint(f);
    return u ^ (((unsigned)((int)u >> 31)) | 0x80000000u);
}
__device__ __forceinline__ float unflipKey(unsigned k) {
    unsigned u = k ^ ((k & 0x80000000u) ? 0x80000000u : 0xFFFFFFFFu);
    return __uint_as_float(u);
}
__device__ __forceinline__ float sigmoidf(float x) {
    return 1.0f / (1.0f + expf(-x));
}

// ---- init: zero coarse histograms + extract (token, weight) lists ----
__global__ void __launch_bounds__(256)
kinit(const float* __restrict__ pm, unsigned* nnz, unsigned* tok, float* wt,
      unsigned* __restrict__ gh) {
    int g = blockIdx.x * 256 + threadIdx.x;
    if (g < NIMG * 4096) gh[g] = 0;            // 32768 threads == exact
    if (g < NC) {
        int c = g;
        int cnt = 0;
        for (int l = 0; l < NL; ++l) {
            float v = pm[c * NL + l];
            if (v != 0.0f) { tok[cnt * NC + c] = l; wt[cnt * NC + c] = v; cnt++; }
        }
        nnz[c] = cnt;
    }
}

// ---- fused scores + centerness + coarse 12-bit histogram (v5, row-wave):
//      wave owns 2 full rows; one float4 load/lane/row (ideal coalescing,
//      ~10x fewer VMEM instr than per-element gathers); sigmoids of all
//      256 tokens staged in wave-private LDS (DS ops wave-ordered, no
//      barrier); lanes then act as classes (64+16 passes). ----
__global__ void __launch_bounds__(512)
kscoreh(const float* __restrict__ dp, const float* __restrict__ cent,
        const unsigned* __restrict__ nnz, const unsigned* __restrict__ tok,
        const float* __restrict__ wt, float* __restrict__ scores,
        unsigned* __restrict__ gh) {
    __shared__ unsigned h[4096];          // 16 KB
    __shared__ float sig[8][2][NL];       // 16 KB, wave-private slices
    int t = threadIdx.x;
    int wid = t >> 6, lane = t & 63;
    for (int i = t; i < 4096; i += 512) h[i] = 0;
    __syncthreads();                      // hist zeroed before any atomic
    long long brow = (long long)blockIdx.x * RPB;
    const float4* dp4 = (const float4*)dp;
    float ctr2[2];
#pragma unroll
    for (int rr = 0; rr < 2; ++rr) {      // stage: sigmoid entire row
        long long row = brow + wid * 2 + rr;
        float4 v = dp4[row * (NL / 4) + lane];
        sig[wid][rr][lane * 4 + 0] = sigmoidf(v.x);
        sig[wid][rr][lane * 4 + 1] = sigmoidf(v.y);
        sig[wid][rr][lane * 4 + 2] = sigmoidf(v.z);
        sig[wid][rr][lane * 4 + 3] = sigmoidf(v.w);
        ctr2[rr] = sigmoidf(cent[row]);   // broadcast load per wave
    }
#pragma unroll
    for (int p = 0; p < 2; ++p) {         // classes 0-63, then 64-79
        int c = lane + p * 64;
        if (c < NC) {
            int m = (int)nnz[c];
            int t0 = (int)tok[c] & 255;
            int t1 = (int)tok[NC + c] & 255;
            int t2 = (int)tok[2 * NC + c] & 255;
            float w0 = wt[c], w1 = wt[NC + c], w2 = wt[2 * NC + c];
#pragma unroll
            for (int rr = 0; rr < 2; ++rr) {
                long long row = brow + wid * 2 + rr;
                const float* sg = sig[wid][rr];
                float acc = 0.0f;
                if (m == 3) {             // identical arithmetic/order
                    float s0 = sg[t0];
                    float s1 = sg[t1];
                    float s2 = sg[t2];
                    acc += s0 * w0; acc += s1 * w1; acc += s2 * w2;
                } else {
                    for (int q = 0; q < m; ++q)
                        acc += sg[(int)tok[q * NC + c] & 255] * wt[q * NC + c];
                }
                float sc = (acc > 0.05f) ? acc * ctr2[rr] : -1.0f;
                scores[row * NC + c] = sc;
                atomicAdd(&h[flipKey(sc) >> 20], 1u);
            }
        }
    }
    __syncthreads();
    int n = (int)(brow / HWQ);            // 950 blocks per image exactly
    for (int i = t; i < 4096; i += 512)
        if (h[i]) atomicAdd(&gh[n * 4096 + i], h[i]);
}

// ---- find coarse bucket containing rank TOPK ----
__global__ void kfind1(const unsigned* __restrict__ gh, unsigned* meta) {
    __shared__ unsigned h[4096];
    __shared__ unsigned psum[256];
    int n = blockIdx.x;
    for (int i = threadIdx.x; i < 4096; i += 256) h[i] = gh[n * 4096 + i];
    __syncthreads();
    unsigned s = 0;
    for (int i = 0; i < 16; ++i) s += h[threadIdx.x * 16 + i];
    psum[threadIdx.x] = s;
    __syncthreads();
    if (threadIdx.x == 0) {
        unsigned cum = 0, above = 0; int B = 0; bool done = false;
        for (int seg = 255; seg >= 0 && !done; --seg) {
            if (cum + psum[seg] >= TOPK) {
                for (int b = seg * 16 + 15; b >= seg * 16; --b) {
                    if (cum + h[b] >= TOPK) { B = b; above = cum; done = true; break; }
                    cum += h[b];
                }
            } else cum += psum[seg];
        }
        meta[n] = (unsigned)B;
        meta[8 + n] = above;
    }
}

// ---- count pass with per-wave 256-bit selection masks (atomic-free) ----
__global__ void __launch_bounds__(256)
kcountM(const float4* __restrict__ scores4, const unsigned* __restrict__ meta,
        unsigned* __restrict__ wavecnt, unsigned long long* __restrict__ wavemask) {
    int i4 = blockIdx.x * 256 + threadIdx.x;
    int n = i4 / PI4;                 // wave-uniform (64 | PI4)
    unsigned B = meta[n];
    float4 v = scores4[i4];
    bool s0 = (flipKey(v.x) >> 20) >= B;
    bool s1 = (flipKey(v.y) >> 20) >= B;
    bool s2 = (flipKey(v.z) >> 20) >= B;
    bool s3 = (flipKey(v.w) >> 20) >= B;
    unsigned long long m0 = __ballot(s0);
    unsigned long long m1 = __ballot(s1);
    unsigned long long m2 = __ballot(s2);
    unsigned long long m3 = __ballot(s3);
    if ((threadIdx.x & 63) == 0) {
        int w = i4 >> 6;
        wavemask[(size_t)w * 4 + 0] = m0;
        wavemask[(size_t)w * 4 + 1] = m1;
        wavemask[(size_t)w * 4 + 2] = m2;
        wavemask[(size_t)w * 4 + 3] = m3;
        wavecnt[w] = (unsigned)(__popcll(m0) + __popcll(m1)
                              + __popcll(m2) + __popcll(m3));
    }
}

// ---- per-image: prefix over wave counts + sparse gather-write of cand ----
__global__ void __launch_bounds__(1024)
kscanW(const unsigned* __restrict__ wavecnt,
       const unsigned long long* __restrict__ wavemask,
       const float* __restrict__ scores,
       unsigned* __restrict__ cnt, unsigned long long* __restrict__ cand) {
    __shared__ unsigned ps[1024];
    int n = blockIdx.x, t = threadIdx.x;
    const unsigned* wc = wavecnt + n * WPI;
    int s0 = t * 5;                    // 5*1024 = 5120 >= 4750
    unsigned loc[5], vv[5]; unsigned sum = 0;
#pragma unroll
    for (int j = 0; j < 5; ++j) {
        int i = s0 + j;
        unsigned x = (i < WPI) ? wc[i] : 0u;
        vv[j] = x; loc[j] = sum; sum += x;
    }
    ps[t] = sum;
    __syncthreads();
    for (int off = 1; off < 1024; off <<= 1) {
        unsigned add = (t >= off) ? ps[t - off] : 0u;
        __syncthreads();
        ps[t] += add;
        __syncthreads();
    }
    unsigned excl = (t > 0) ? ps[t - 1] : 0u;
    if (t == 1023) cnt[n] = ps[1023];
    const float* sb = scores + (size_t)n * PERIMG;
    unsigned long long* cb = cand + (size_t)n * CAP;
#pragma unroll
    for (int j = 0; j < 5; ++j) {
        int wl = s0 + j;
        if (wl < WPI && vv[j]) {       // ~5% of waves non-empty
            unsigned off = excl + loc[j];
            const unsigned long long* mk = wavemask + ((size_t)(n * WPI + wl)) * 4;
#pragma unroll
            for (int e = 0; e < 4; ++e) {
                unsigned long long m = mk[e];
                while (m) {
                    int b = __ffsll(m) - 1; m &= m - 1;
                    int li = wl * 256 + b * 4 + e;
                    unsigned key = flipKey(sb[li]);
                    if (off < CAP)
                        cb[off] = ((unsigned long long)key << 32)
                                  | (unsigned)(~li);
                    off++;
                }
            }
        }
    }
}

// ---- fallback 3-pass compaction (used only if ws too small for masks) ----
__global__ void __launch_bounds__(256)
kcount(const float4* __restrict__ scores4, const unsigned* __restrict__ meta,
       unsigned* __restrict__ wavecnt) {
    int i4 = blockIdx.x * 256 + threadIdx.x;
    int n = i4 / PI4;
    unsigned B = meta[n];
    float4 v = scores4[i4];
    int ns = 0;
    ns += ((flipKey(v.x) >> 20) >= B);
    ns += ((flipKey(v.y) >> 20) >= B);
    ns += ((flipKey(v.z) >> 20) >= B);
    ns += ((flipKey(v.w) >> 20) >= B);
    int s = ns;
#pragma unroll
    for (int off = 1; off < 64; off <<= 1) s += __shfl_xor(s, off);
    if ((threadIdx.x & 63) == 0) wavecnt[i4 >> 6] = (unsigned)s;
}
__global__ void __launch_bounds__(1024)
kscan(const unsigned* __restrict__ wavecnt, unsigned* __restrict__ waveoff,
      unsigned* __restrict__ cnt) {
    __shared__ unsigned ps[1024];
    int n = blockIdx.x, t = threadIdx.x;
    const unsigned* wc = wavecnt + n * WPI;
    unsigned* wo = waveoff + n * WPI;
    int s0 = t * 5;
    unsigned loc[5]; unsigned sum = 0;
#pragma unroll
    for (int j = 0; j < 5; ++j) {
        int i = s0 + j;
        unsigned vv = (i < WPI) ? wc[i] : 0u;
        loc[j] = sum; sum += vv;
    }
    ps[t] = sum;
    __syncthreads();
    for (int off = 1; off < 1024; off <<= 1) {
        unsigned add = (t >= off) ? ps[t - off] : 0u;
        __syncthreads();
        ps[t] += add;
        __syncthreads();
    }
    unsigned excl = (t > 0) ? ps[t - 1] : 0u;
#pragma unroll
    for (int j = 0; j < 5; ++j) {
        int i = s0 + j;
        if (i < WPI) wo[i] = excl + loc[j];
    }
    if (t == 1023) cnt[n] = ps[1023];
}
__global__ void __launch_bounds__(256)
kwrite(const float4* __restrict__ scores4, const unsigned* __restrict__ meta,
       const unsigned* __restrict__ waveoff, unsigned long long* __restrict__ cand) {
    int i4 = blockIdx.x * 256 + threadIdx.x;
    int n = i4 / PI4;
    unsigned B = meta[n];
    float4 v = scores4[i4];
    int li0 = (i4 - n * PI4) * 4;
    unsigned keys[4]; int sel[4]; int ns = 0;
    keys[0] = flipKey(v.x); sel[0] = (keys[0] >> 20) >= B; ns += sel[0];
    keys[1] = flipKey(v.y); sel[1] = (keys[1] >> 20) >= B; ns += sel[1];
    keys[2] = flipKey(v.z); sel[2] = (keys[2] >> 20) >= B; ns += sel[2];
    keys[3] = flipKey(v.w); sel[3] = (keys[3] >> 20) >= B; ns += sel[3];
    int lane = threadIdx.x & 63;
    int pre = ns;
#pragma unroll
    for (int off = 1; off < 64; off <<= 1) {
        int o = __shfl_up(pre, off);
        if (lane >= off) pre += o;
    }
    unsigned base = waveoff[i4 >> 6] + (unsigned)(pre - ns);
    unsigned long long* cbase = cand + (size_t)n * CAP;
#pragma unroll
    for (int e = 0; e < 4; ++e) {
        if (sel[e]) {
            if (base < CAP)
                cbase[base] = ((unsigned long long)keys[e] << 32)
                              | (unsigned)(~(li0 + e));
            base++;
        }
    }
}

// ---- fine threshold over compacted candidates + small exact sort ----
__global__ void __launch_bounds__(1024)
kfine(const unsigned long long* __restrict__ cand, const unsigned* __restrict__ cnt,
      const unsigned* __restrict__ meta, unsigned long long* __restrict__ sorted) {
    __shared__ unsigned h[4096];                 // 16 KB
    __shared__ unsigned long long sbuf[SSORT];   // 16 KB
    __shared__ unsigned psum[256];
    __shared__ unsigned selcnt;
    __shared__ unsigned Fbin;
    int n = blockIdx.x, t = threadIdx.x;
    int M = min(cnt[n], (unsigned)CAP);
    unsigned B = meta[n], above = meta[8 + n];
    const unsigned long long* cb = cand + (size_t)n * CAP;
    for (int i = t; i < 4096; i += 1024) h[i] = 0;
    sbuf[t] = 0ULL; sbuf[t + 1024] = 0ULL;
    if (t == 0) selcnt = 0;
    __syncthreads();
    for (int i = t; i < M; i += 1024) {
        unsigned key = (unsigned)(cb[i] >> 32);
        if ((key >> 20) == B) atomicAdd(&h[(key >> 8) & 0xFFFu], 1u);
    }
    __syncthreads();
    if (t < 256) {
        unsigned s = 0;
        for (int i = 0; i < 16; ++i) s += h[t * 16 + i];
        psum[t] = s;
    }
    __syncthreads();
    if (t == 0) {
        unsigned cum = above; int F = 0; bool done = false;
        for (int seg = 255; seg >= 0 && !done; --seg) {
            if (cum + psum[seg] >= TOPK) {
                for (int b = seg * 16 + 15; b >= seg * 16; --b) {
                    if (cum + h[b] >= TOPK) { F = b; done = true; break; }
                    cum += h[b];
                }
            } else cum += psum[seg];
        }
        Fbin = (unsigned)F;
    }
    __syncthreads();
    unsigned T24 = (B << 12) | Fbin;
    for (int i = t; i < M; i += 1024) {
        unsigned long long e = cb[i];
        unsigned key = (unsigned)(e >> 32);
        if ((key >> 8) >= T24) {
            unsigned p = atomicAdd(&selcnt, 1u);   // order irrelevant: full sort follows
            if (p < SSORT) sbuf[p] = e;
        }
    }
    __syncthreads();
    int s = (int)selcnt;
    int SN = (s <= 1024) ? 1024 : SSORT;
    for (int k = 2; k <= SN; k <<= 1) {
        for (int j = k >> 1; j > 0; j >>= 1) {
            for (int i = t; i < SN; i += 1024) {
                int l = i ^ j;
                if (l > i) {
                    unsigned long long a = sbuf[i], b = sbuf[l];
                    bool sw = ((i & k) == 0) ? (a < b) : (a > b);
                    if (sw) { sbuf[i] = b; sbuf[l] = a; }
                }
            }
            __syncthreads();
        }
    }
    if (t < TOPK) sorted[(n << 10) + t] = sbuf[t];
}

// ---- decode all 8x1000 candidates chip-wide ----
__global__ void __launch_bounds__(256)
kdecode(const unsigned long long* __restrict__ sorted,
        const float* __restrict__ anchors, const float* __restrict__ breg,
        float4* __restrict__ box4, float4* __restrict__ obx4,
        float* __restrict__ areag, unsigned* __restrict__ lblkeep) {
    int gid = blockIdx.x * 256 + threadIdx.x;
    if (gid >= NIMG * TOPK) return;
    int n = gid / TOPK, r = gid - n * TOPK;
    int o = (n << 10) + r;
    unsigned long long e = sorted[o];
    unsigned key = (unsigned)(e >> 32);
    bool real = key > 0x80000000u;       // masked value > 0
    unsigned li = ~(unsigned)(e & 0xFFFFFFFFu);
    unsigned k = li / NC, c = li - k * NC;
    int label = (int)c + 1;
    float x1 = 0, y1 = 0, x2 = 0, y2 = 0;
    bool val = false;
    if (real) {
        float a0 = anchors[k * 4 + 0], a1 = anchors[k * 4 + 1];
        float a2 = anchors[k * 4 + 2], a3 = anchors[k * 4 + 3];
        float r0 = breg[(n * 4 + 0) * HWQ + k];
        float r1 = breg[(n * 4 + 1) * HWQ + k];
        float r2 = breg[(n * 4 + 2) * HWQ + k];
        float r3 = breg[(n * 4 + 3) * HWQ + k];
        float aw = a2 - a0, ah = a3 - a1;
        float acx = a0 + 0.5f * aw, acy = a1 + 0.5f * ah;
        float dx = r0 / 10.0f, dy = r1 / 10.0f;
        float dw = fminf(r2 / 5.0f, 4.135166556742356f);
        float dh = fminf(r3 / 5.0f, 4.135166556742356f);
        float pcx = dx * aw + acx, pcy = dy * ah + acy;
        float pw = expf(dw) * aw, ph = expf(dh) * ah;
        x1 = fminf(fmaxf(pcx - 0.5f * pw, 0.0f), 1216.0f);
        y1 = fminf(fmaxf(pcy - 0.5f * ph, 0.0f), 800.0f);
        x2 = fminf(fmaxf(pcx + 0.5f * pw, 0.0f), 1216.0f);
        y2 = fminf(fmaxf(pcy + 0.5f * ph, 0.0f), 800.0f);
        val = (x2 - x1 > 0.0f) && (y2 - y1 > 0.0f);
    }
    box4[o] = make_float4(x1, y1, x2, y2);
    float off = (float)label * 10000.0f;   // replicate offset-then-round
    float o0 = x1 + off, o1 = y1 + off, o2 = x2 + off, o3 = y2 + off;
    obx4[o] = make_float4(o0, o1, o2, o3);
    areag[o] = (o2 - o0) * (o3 - o1);
    lblkeep[o] = (unsigned)(real ? label : 0) | ((val ? 1u : 0u) << 16);
}

// ---- per-image: class-decomposed bitmask NMS + output ----
__global__ void __launch_bounds__(1024)
knms2(const unsigned long long* __restrict__ sorted,
      const float4* __restrict__ obx4, const float* __restrict__ areag,
      const unsigned* __restrict__ lblkeep, const float4* __restrict__ box4,
      float* __restrict__ outBoxes, float* __restrict__ outScores,
      float* __restrict__ outLabels) {
    __shared__ float ob0[TOPK], ob1[TOPK], ob2[TOPK], ob3[TOPK], area[TOPK];
    __shared__ unsigned long long sup[TOPK];
    __shared__ unsigned short lbl[TOPK];
    __shared__ unsigned char  keepf[TOPK];
    __shared__ unsigned short wrank[TOPK];
    __shared__ unsigned short clist[TOPK];
    __shared__ unsigned short cstart[NC + 1];
    __shared__ unsigned ccnt[NC];
    __shared__ int pfx[1024];
    __shared__ int smax;

    int n = blockIdx.x, t = threadIdx.x;
    if (t < NC) ccnt[t] = 0;
    if (t == 0) smax = 0;
    if (t < TOPK) {
        int o = (n << 10) + t;
        float4 ob = obx4[o];
        ob0[t] = ob.x; ob1[t] = ob.y; ob2[t] = ob.z; ob3[t] = ob.w;
        area[t] = areag[o];
        unsigned lk = lblkeep[o];
        lbl[t] = (unsigned short)(lk & 0xFFFFu);
        keepf[t] = (unsigned char)(lk >> 16);
        sup[t] = 0ULL;
    }
    __syncthreads();

    if (t < TOPK) {
        unsigned short my = lbl[t];
        int w = 0;
        if (my) {
            for (int r = 0; r < t; ++r) w += (lbl[r] == my);
            atomicAdd(&ccnt[my - 1], 1u);
        }
        wrank[t] = (unsigned short)w;
    }
    __syncthreads();
    if (t < NC) atomicMax(&smax, (int)ccnt[t]);
    __syncthreads();
    if (t == 0) {
        unsigned s = 0;
        for (int c = 0; c < NC; ++c) { cstart[c] = (unsigned short)s; s += ccnt[c]; }
        cstart[NC] = (unsigned short)s;
    }
    __syncthreads();
    if (t < TOPK && lbl[t]) clist[cstart[lbl[t] - 1] + wrank[t]] = (unsigned short)t;
    __syncthreads();

    if (smax <= 64) {
        if (t < TOPK && lbl[t]) {
            int base = cstart[lbl[t] - 1];
            int w = wrank[t];
            float A0 = ob0[t], A1 = ob1[t], A2 = ob2[t], A3 = ob3[t], Aa = area[t];
            unsigned long long m = 0ULL;
            for (int j = 0; j < w; ++j) {
                int ib = clist[base + j];
                float iw = fminf(A2, ob2[ib]) - fmaxf(A0, ob0[ib]);
                float ih = fminf(A3, ob3[ib]) - fmaxf(A1, ob1[ib]);
                float inter = fmaxf(iw, 0.0f) * fmaxf(ih, 0.0f);
                float denom = Aa + area[ib] - inter + 1e-6f;
                if (inter / denom > 0.6f) m |= (1ull << j);
            }
            sup[t] = m;
        }
        __syncthreads();
        if (t < NC) {
            unsigned long long kb = 0ULL;
            int base = cstart[t], mc = (int)ccnt[t];
            for (int w = 0; w < mc; ++w) {
                int i = clist[base + w];
                bool kp = keepf[i] && ((sup[i] & kb) == 0ULL);
                keepf[i] = kp ? 1 : 0;
                if (kp) kb |= (1ull << w);
            }
        }
    } else {
        __syncthreads();
        if (t < NC) {
            int s0 = cstart[t], s1 = s0 + (int)ccnt[t];
            for (int a = s0; a < s1; ++a) {
                int ia = clist[a];
                if (!keepf[ia]) continue;
                float A0 = ob0[ia], A1 = ob1[ia], A2 = ob2[ia], A3 = ob3[ia];
                float Aa = area[ia];
                for (int b = a + 1; b < s1; ++b) {
                    int ib = clist[b];
                    if (!keepf[ib]) continue;
                    float iw = fminf(A2, ob2[ib]) - fmaxf(A0, ob0[ib]);
                    float ih = fminf(A3, ob3[ib]) - fmaxf(A1, ob1[ib]);
                    float inter = fmaxf(iw, 0.0f) * fmaxf(ih, 0.0f);
                    float denom = Aa + area[ib] - inter + 1e-6f;
                    if (inter / denom > 0.6f) keepf[ib] = 0;
                }
            }
        }
    }
    __syncthreads();

    pfx[t] = (t < TOPK) ? (int)keepf[t] : 0;
    __syncthreads();
    for (int off = 1; off < 1024; off <<= 1) {
        int add = (t >= off) ? pfx[t - off] : 0;
        __syncthreads();
        pfx[t] += add;
        __syncthreads();
    }
    int total = pfx[1023];

    if (t < TOPK && keepf[t]) {
        int q = pfx[t] - 1;
        if (q < NPOST) {
            int o = (n << 10) + t;
            float4 b = box4[o];
            float fused = unflipKey((unsigned)(sorted[o] >> 32));
            outBoxes[(n * NPOST + q) * 4 + 0] = b.x;
            outBoxes[(n * NPOST + q) * 4 + 1] = b.y;
            outBoxes[(n * NPOST + q) * 4 + 2] = b.z;
            outBoxes[(n * NPOST + q) * 4 + 3] = b.w;
            outScores[n * NPOST + q] = sqrtf(fmaxf(fused, 0.0f));
            outLabels[n * NPOST + q] = (float)lbl[t];
        }
    }
    if (t < NPOST && t >= total) {
        outBoxes[(n * NPOST + t) * 4 + 0] = 0.0f;
        outBoxes[(n * NPOST + t) * 4 + 1] = 0.0f;
        outBoxes[(n * NPOST + t) * 4 + 2] = 0.0f;
        outBoxes[(n * NPOST + t) * 4 + 3] = 0.0f;
        outScores[n * NPOST + t] = 0.0f;
        outLabels[n * NPOST + t] = 0.0f;
    }
}

extern "C" void kernel_launch(void* const* d_in, const int* in_sizes, int n_in,
                              void* d_out, int out_size, void* d_ws, size_t ws_size,
                              hipStream_t stream) {
    const float* breg = (const float*)d_in[0];   // [8,4,100,152]
    const float* cent = (const float*)d_in[1];   // [8,1,100,152]
    // d_in[2] box_cls: unused by reference
    const float* dp   = (const float*)d_in[3];   // [8,15200,256]
    const float* anc  = (const float*)d_in[4];   // [15200,4]
    const float* pm   = (const float*)d_in[5];   // [80,256]

    char* ws = (char*)d_ws;
    size_t off_scores  = 0;                                    // 38,912,000
    size_t off_gh      = off_scores + (size_t)TOTAL * 4;       // 131,072
    size_t off_cnt     = off_gh + (size_t)NIMG * 4096 * 4;     // 32 (pad 128)
    size_t off_meta    = off_cnt + 128;                        // 64 (pad 128)
    size_t off_cand    = off_meta + 128;                       // 262,144
    size_t off_nnz     = off_cand + (size_t)NIMG * CAP * 8;    // 320 (pad 512)
    size_t off_tok     = off_nnz + 512;                        // 81,920
    size_t off_wt      = off_tok + (size_t)NC * NL * 4;        // 81,920
    size_t off_wavecnt = off_wt + (size_t)NC * NL * 4;         // 152,000 (+64)
    size_t off_tail    = off_wavecnt + (size_t)NWAVE * 4 + 64; // mask OR waveoff
    size_t needed_new  = off_tail + (size_t)NWAVE * 32;        // masks: 1.216MB
    size_t needed_old  = off_tail + (size_t)NWAVE * 4 + 64;    // waveoff
    if (ws_size < needed_old) return;
    bool useMask = ws_size >= needed_new;

    // post-compaction arrays alias the scores region (scores dead after
    // compaction; rewritten from scratch by kscoreh each replay)
    size_t off_sorted = off_scores;                            // 65,536
    size_t off_box4   = off_sorted + (size_t)NIMG * 1024 * 8;  // 131,072
    size_t off_obx4   = off_box4 + (size_t)NIMG * 1024 * 16;   // 131,072
    size_t off_area   = off_obx4 + (size_t)NIMG * 1024 * 16;   // 32,768
    size_t off_lblk   = off_area + (size_t)NIMG * 1024 * 4;    // 32,768

    float*    scores  = (float*)(ws + off_scores);
    unsigned* gh      = (unsigned*)(ws + off_gh);
    unsigned* cnt     = (unsigned*)(ws + off_cnt);
    unsigned* meta    = (unsigned*)(ws + off_meta);
    unsigned long long* cand = (unsigned long long*)(ws + off_cand);
    unsigned* nnz     = (unsigned*)(ws + off_nnz);
    unsigned* tok     = (unsigned*)(ws + off_tok);
    float*    wt      = (float*)(ws + off_wt);
    unsigned* wavecnt = (unsigned*)(ws + off_wavecnt);
    unsigned long long* wavemask = (unsigned long long*)(ws + off_tail);
    unsigned* waveoff = (unsigned*)(ws + off_tail);
    unsigned long long* sorted = (unsigned long long*)(ws + off_sorted);
    float4*   box4    = (float4*)(ws + off_box4);
    float4*   obx4    = (float4*)(ws + off_obx4);
    float*    areag   = (float*)(ws + off_area);
    unsigned* lblkeep = (unsigned*)(ws + off_lblk);

    kinit<<<128, 256, 0, stream>>>(pm, nnz, tok, wt, gh);
    kscoreh<<<SBLKR, 512, 0, stream>>>(dp, cent, nnz, tok, wt, scores, gh);
    kfind1<<<NIMG, 256, 0, stream>>>(gh, meta);
    if (useMask) {
        kcountM<<<CBLK, 256, 0, stream>>>((const float4*)scores, meta,
                                          wavecnt, wavemask);
        kscanW<<<NIMG, 1024, 0, stream>>>(wavecnt, wavemask, scores, cnt, cand);
    } else {
        kcount<<<CBLK, 256, 0, stream>>>((const float4*)scores, meta, wavecnt);
        kscan<<<NIMG, 1024, 0, stream>>>(wavecnt, waveoff, cnt);
        kwrite<<<CBLK, 256, 0, stream>>>((const float4*)scores, meta, waveoff, cand);
    }
    kfine<<<NIMG, 1024, 0, stream>>>(cand, cnt, meta, sorted);
    kdecode<<<(NIMG * TOPK + 255) / 256, 256, 0, stream>>>(sorted, anc, breg,
                                                           box4, obx4, areag, lblkeep);

    float* outBoxes  = (float*)d_out;                       // 8*100*4
    float* outScores = outBoxes + NIMG * NPOST * 4;         // 8*100
    float* outLabels = outScores + NIMG * NPOST;            // 8*100
    knms2<<<NIMG, 1024, 0, stream>>>(sorted, obx4, areag, lblkeep, box4,
                                     outBoxes, outScores, outLabels);
}

// Round 12
// 211.839 us; speedup vs baseline: 1.0038x; 1.0038x over previous
//
#include <hip/hip_runtime.h>
#include <hip/hip_bf16.h>

#define NIMG 8
#define NC   80
#define NL   256
#define HWQ  15200
#define TOPK 1000
#define SSORT 2048
#define NPOST 100
#define PERIMG (HWQ * NC)          // 1,216,000
#define TOTAL (NIMG * PERIMG)      // 9,728,000
#define SROW 32                    // rows per score block
#define SBLK32 (NIMG * HWQ / SROW) // 3800
#define PI4  (PERIMG / 4)          // 304,000 float4 per image
#define WPI  (PI4 / 64)            // 4750 waves per image
#define NWAVE (NIMG * WPI)         // 38,000
#define CBLK (TOTAL / 4 / 256)     // 9,500 blocks for count pass

__device__ __forceinline__ unsigned flipKey(float f) {
    unsigned u = __float_as_uint(f);
    return u ^ (((unsigned)((int)u >> 31)) | 0x80000000u);
}
__device__ __forceinline__ float unflipKey(unsigned k) {
    unsigned u = k ^ ((k & 0x80000000u) ? 0x80000000u : 0xFFFFFFFFu);
    return __uint_as_float(u);
}
__device__ __forceinline__ float sigmoidf(float x) {
    return 1.0f / (1.0f + expf(-x));
}

// ---- init: zero coarse histograms + extract (token, weight) lists ----
__global__ void __launch_bounds__(256)
kinit(const float* __restrict__ pm, unsigned* nnz, unsigned* tok, float* wt,
      unsigned* __restrict__ gh) {
    int g = blockIdx.x * 256 + threadIdx.x;
    if (g < NIMG * 4096) gh[g] = 0;            // 32768 threads == exact
    if (g < NC) {
        int c = g;
        int cnt = 0;
        for (int l = 0; l < NL; ++l) {
            float v = pm[c * NL + l];
            if (v != 0.0f) { tok[cnt * NC + c] = l; wt[cnt * NC + c] = v; cnt++; }
        }
        nnz[c] = cnt;
    }
}

// ---- fused scores + centerness + coarse 12-bit histogram (v3, round-10):
//      512 thr x 32 rows, float3 gather for consecutive tokens, 5-elem ILP ----
__global__ void __launch_bounds__(512)
kscoreh(const float* __restrict__ dp, const float* __restrict__ cent,
        const unsigned* __restrict__ nnz, const unsigned* __restrict__ tok,
        const float* __restrict__ wt, float* __restrict__ scores,
        unsigned* __restrict__ gh) {
    __shared__ unsigned h[4096];        // 16 KB
    __shared__ float sctr[SROW];
    int t = threadIdx.x;
    for (int i = t; i < 4096; i += 512) h[i] = 0;
    long long base = (long long)blockIdx.x * SROW;        // first global row
    if (t < SROW) sctr[t] = sigmoidf(cent[base + t]);     // once per row
    long long obase = base * NC;
    const float* dpb = dp + base * NL;

    int  rr[5], cc[5], mm[5];
    int  tk[5][3];
    float wv[5][3], xv[5][3];
#pragma unroll
    for (int j = 0; j < 5; ++j) {
        int o = t + j * 512;            // 0..2559 (32 rows x 80 classes)
        rr[j] = o / NC; cc[j] = o - rr[j] * NC;
        mm[j] = (int)nnz[cc[j]];
        int c = cc[j];
        tk[j][0] = (int)tok[c] & 255;           // clamp: safe vs stale ws
        tk[j][1] = (int)tok[NC + c] & 255;
        tk[j][2] = (int)tok[2 * NC + c] & 255;
        wv[j][0] = wt[c]; wv[j][1] = wt[NC + c]; wv[j][2] = wt[2 * NC + c];
    }
#pragma unroll
    for (int j = 0; j < 5; ++j) {       // all gathers issued before any exp
        const float* row = dpb + rr[j] * NL;
        if (tk[j][1] == tk[j][0] + 1 && tk[j][2] == tk[j][0] + 2) {
            float3 v3 = *(const float3*)(row + tk[j][0]);   // 1 VMEM, 12B
            xv[j][0] = v3.x; xv[j][1] = v3.y; xv[j][2] = v3.z;
        } else {
            xv[j][0] = row[tk[j][0]];
            xv[j][1] = row[tk[j][1]];
            xv[j][2] = row[tk[j][2]];
        }
    }
    __syncthreads();                    // sctr ready; hist zeroed
#pragma unroll
    for (int j = 0; j < 5; ++j) {
        float acc = 0.0f;
        if (mm[j] == 3) {               // identical arithmetic to prior rounds
            float s0 = sigmoidf(xv[j][0]);
            float s1 = sigmoidf(xv[j][1]);
            float s2 = sigmoidf(xv[j][2]);
            acc += s0 * wv[j][0]; acc += s1 * wv[j][1]; acc += s2 * wv[j][2];
        } else {
            const float* row = dpb + rr[j] * NL;
            for (int q = 0; q < mm[j]; ++q)
                acc += sigmoidf(row[tok[q * NC + cc[j]]]) * wt[q * NC + cc[j]];
        }
        float sc = (acc > 0.05f) ? acc * sctr[rr[j]] : -1.0f;
        scores[obase + t + j * 512] = sc;
        atomicAdd(&h[flipKey(sc) >> 20], 1u);
    }
    __syncthreads();
    int n = (int)(base / HWQ);          // 475 blocks per image exactly
    for (int i = t; i < 4096; i += 512)
        if (h[i]) atomicAdd(&gh[n * 4096 + i], h[i]);
}

// ---- find coarse bucket containing rank TOPK ----
__global__ void kfind1(const unsigned* __restrict__ gh, unsigned* meta) {
    __shared__ unsigned h[4096];
    __shared__ unsigned psum[256];
    int n = blockIdx.x;
    for (int i = threadIdx.x; i < 4096; i += 256) h[i] = gh[n * 4096 + i];
    __syncthreads();
    unsigned s = 0;
    for (int i = 0; i < 16; ++i) s += h[threadIdx.x * 16 + i];
    psum[threadIdx.x] = s;
    __syncthreads();
    if (threadIdx.x == 0) {
        unsigned cum = 0, above = 0; int B = 0; bool done = false;
        for (int seg = 255; seg >= 0 && !done; --seg) {
            if (cum + psum[seg] >= TOPK) {
                for (int b = seg * 16 + 15; b >= seg * 16; --b) {
                    if (cum + h[b] >= TOPK) { B = b; above = cum; done = true; break; }
                    cum += h[b];
                }
            } else cum += psum[seg];
        }
        meta[n] = (unsigned)B;
        meta[8 + n] = above;
    }
}

// ---- count pass with per-wave 256-bit selection masks (atomic-free) ----
__global__ void __launch_bounds__(256)
kcountM(const float4* __restrict__ scores4, const unsigned* __restrict__ meta,
        unsigned* __restrict__ wavecnt, unsigned long long* __restrict__ wavemask) {
    int i4 = blockIdx.x * 256 + threadIdx.x;
    int n = i4 / PI4;                 // wave-uniform (64 | PI4)
    unsigned B = meta[n];
    float4 v = scores4[i4];
    bool s0 = (flipKey(v.x) >> 20) >= B;
    bool s1 = (flipKey(v.y) >> 20) >= B;
    bool s2 = (flipKey(v.z) >> 20) >= B;
    bool s3 = (flipKey(v.w) >> 20) >= B;
    unsigned long long m0 = __ballot(s0);
    unsigned long long m1 = __ballot(s1);
    unsigned long long m2 = __ballot(s2);
    unsigned long long m3 = __ballot(s3);
    if ((threadIdx.x & 63) == 0) {
        int w = i4 >> 6;
        wavemask[(size_t)w * 4 + 0] = m0;
        wavemask[(size_t)w * 4 + 1] = m1;
        wavemask[(size_t)w * 4 + 2] = m2;
        wavemask[(size_t)w * 4 + 3] = m3;
        wavecnt[w] = (unsigned)(__popcll(m0) + __popcll(m1)
                              + __popcll(m2) + __popcll(m3));
    }
}

// ---- fused per-image tail: fine threshold (from masks, no cand array),
//      exact sort, decode, class-decomposed bitmask NMS, output ----
__global__ void __launch_bounds__(1024)
ktail(const unsigned* __restrict__ wavecnt,
      const unsigned long long* __restrict__ wavemask,
      const float* __restrict__ scores, const unsigned* __restrict__ meta,
      const float* __restrict__ anchors, const float* __restrict__ breg,
      float* __restrict__ outBoxes, float* __restrict__ outScores,
      float* __restrict__ outLabels) {
    __shared__ unsigned long long sbuf[SSORT];   // 16 KB
    __shared__ unsigned uover[4096];             // 16 KB: hist, then ob0..ob3
    __shared__ float area[TOPK];                 // 4 KB
    __shared__ unsigned long long sup[TOPK];     // 8 KB
    __shared__ unsigned short lbl[TOPK];
    __shared__ unsigned char  keepf[TOPK];
    __shared__ unsigned short wrank[TOPK];
    __shared__ unsigned short clist[TOPK];
    __shared__ unsigned short cstart[NC + 1];
    __shared__ unsigned ccnt[NC];
    __shared__ int pfx[1024];                    // 4 KB (also psum scratch)
    __shared__ unsigned selcnt, FbinS;
    __shared__ int smax;

    int n = blockIdx.x, t = threadIdx.x;
    unsigned B = meta[n], above = meta[8 + n];
    const unsigned* wc = wavecnt + n * WPI;
    const unsigned long long* wm = wavemask + (size_t)n * WPI * 4;
    const float* sb = scores + (size_t)n * PERIMG;

    unsigned* h = uover;
    for (int i = t; i < 4096; i += 1024) h[i] = 0;
    sbuf[t] = 0ULL; sbuf[t + 1024] = 0ULL;
    if (t == 0) { selcnt = 0; smax = 0; }
    if (t < NC) ccnt[t] = 0;
    __syncthreads();

    // phase 1: fine histogram (bits 19:8) over mask-selected, bucket==B
    for (int wl = t; wl < WPI; wl += 1024) {
        if (wc[wl]) {
#pragma unroll
            for (int e = 0; e < 4; ++e) {
                unsigned long long m = wm[(size_t)wl * 4 + e];
                while (m) {
                    int b = __ffsll(m) - 1; m &= m - 1;
                    unsigned key = flipKey(sb[wl * 256 + b * 4 + e]);
                    if ((key >> 20) == B) atomicAdd(&h[(key >> 8) & 0xFFFu], 1u);
                }
            }
        }
    }
    __syncthreads();

    // phase 2: find fine bucket -> 24-bit threshold
    unsigned* psum = (unsigned*)pfx;
    if (t < 256) {
        unsigned s = 0;
        for (int i = 0; i < 16; ++i) s += h[t * 16 + i];
        psum[t] = s;
    }
    __syncthreads();
    if (t == 0) {
        unsigned cum = above; int F = 0; bool done = false;
        for (int seg = 255; seg >= 0 && !done; --seg) {
            if (cum + psum[seg] >= TOPK) {
                for (int b = seg * 16 + 15; b >= seg * 16; --b) {
                    if (cum + h[b] >= TOPK) { F = b; done = true; break; }
                    cum += h[b];
                }
            } else cum += psum[seg];
        }
        FbinS = (unsigned)F;
    }
    __syncthreads();
    unsigned T24 = (B << 12) | FbinS;

    // phase 3: select >= T24 into sbuf (order irrelevant: full sort next)
    for (int wl = t; wl < WPI; wl += 1024) {
        if (wc[wl]) {
#pragma unroll
            for (int e = 0; e < 4; ++e) {
                unsigned long long m = wm[(size_t)wl * 4 + e];
                while (m) {
                    int b = __ffsll(m) - 1; m &= m - 1;
                    int li = wl * 256 + b * 4 + e;
                    unsigned key = flipKey(sb[li]);
                    if ((key >> 8) >= T24) {
                        unsigned p = atomicAdd(&selcnt, 1u);
                        if (p < SSORT)
                            sbuf[p] = ((unsigned long long)key << 32)
                                      | (unsigned)(~li);
                    }
                }
            }
        }
    }
    __syncthreads();

    // phase 4: bitonic sort descending on unique (key<<32)|~idx
    int SN = ((int)selcnt <= 1024) ? 1024 : SSORT;
    for (int k = 2; k <= SN; k <<= 1) {
        for (int j = k >> 1; j > 0; j >>= 1) {
            for (int i = t; i < SN; i += 1024) {
                int l = i ^ j;
                if (l > i) {
                    unsigned long long a = sbuf[i], b = sbuf[l];
                    bool sw = ((i & k) == 0) ? (a < b) : (a > b);
                    if (sw) { sbuf[i] = b; sbuf[l] = a; }
                }
            }
            __syncthreads();
        }
    }

    // phase 5: decode top-1000 -> LDS NMS arrays (hist dead; uover = ob0..3)
    float* ob0 = (float*)uover;
    float* ob1 = ob0 + TOPK;
    float* ob2 = ob1 + TOPK;
    float* ob3 = ob2 + TOPK;
    if (t < TOPK) {
        unsigned long long e = sbuf[t];
        unsigned key = (unsigned)(e >> 32);
        bool real = key > 0x80000000u;       // masked value > 0
        unsigned li = ~(unsigned)(e & 0xFFFFFFFFu);
        unsigned k = li / NC, c = li - k * NC;
        int label = (int)c + 1;
        float x1 = 0, y1 = 0, x2 = 0, y2 = 0;
        bool val = false;
        if (real) {
            float a0 = anchors[k * 4 + 0], a1 = anchors[k * 4 + 1];
            float a2 = anchors[k * 4 + 2], a3 = anchors[k * 4 + 3];
            float r0 = breg[(n * 4 + 0) * HWQ + k];
            float r1 = breg[(n * 4 + 1) * HWQ + k];
            float r2 = breg[(n * 4 + 2) * HWQ + k];
            float r3 = breg[(n * 4 + 3) * HWQ + k];
            float aw = a2 - a0, ah = a3 - a1;
            float acx = a0 + 0.5f * aw, acy = a1 + 0.5f * ah;
            float dx = r0 / 10.0f, dy = r1 / 10.0f;
            float dw = fminf(r2 / 5.0f, 4.135166556742356f);
            float dh = fminf(r3 / 5.0f, 4.135166556742356f);
            float pcx = dx * aw + acx, pcy = dy * ah + acy;
            float pw = expf(dw) * aw, ph = expf(dh) * ah;
            x1 = fminf(fmaxf(pcx - 0.5f * pw, 0.0f), 1216.0f);
            y1 = fminf(fmaxf(pcy - 0.5f * ph, 0.0f), 800.0f);
            x2 = fminf(fmaxf(pcx + 0.5f * pw, 0.0f), 1216.0f);
            y2 = fminf(fmaxf(pcy + 0.5f * ph, 0.0f), 800.0f);
            val = (x2 - x1 > 0.0f) && (y2 - y1 > 0.0f);
        }
        float off = (float)label * 10000.0f;   // replicate offset-then-round
        ob0[t] = x1 + off; ob1[t] = y1 + off;
        ob2[t] = x2 + off; ob3[t] = y2 + off;
        area[t] = (ob2[t] - ob0[t]) * (ob3[t] - ob1[t]);
        lbl[t] = real ? (unsigned short)label : (unsigned short)0;
        keepf[t] = val ? 1 : 0;
        sup[t] = 0ULL;
    }
    __syncthreads();

    // phase 6: within-class rank + counts
    if (t < TOPK) {
        unsigned short my = lbl[t];
        int w = 0;
        if (my) {
            for (int r = 0; r < t; ++r) w += (lbl[r] == my);
            atomicAdd(&ccnt[my - 1], 1u);
        }
        wrank[t] = (unsigned short)w;
    }
    __syncthreads();
    if (t < NC) atomicMax(&smax, (int)ccnt[t]);
    __syncthreads();
    if (t == 0) {
        unsigned s = 0;
        for (int c = 0; c < NC; ++c) { cstart[c] = (unsigned short)s; s += ccnt[c]; }
        cstart[NC] = (unsigned short)s;
    }
    __syncthreads();
    if (t < TOPK && lbl[t]) clist[cstart[lbl[t] - 1] + wrank[t]] = (unsigned short)t;
    __syncthreads();

    // phase 7: NMS
    if (smax <= 64) {
        if (t < TOPK && lbl[t]) {
            int base = cstart[lbl[t] - 1];
            int w = wrank[t];
            float A0 = ob0[t], A1 = ob1[t], A2 = ob2[t], A3 = ob3[t], Aa = area[t];
            unsigned long long m = 0ULL;
            for (int j = 0; j < w; ++j) {
                int ib = clist[base + j];
                float iw = fminf(A2, ob2[ib]) - fmaxf(A0, ob0[ib]);
                float ih = fminf(A3, ob3[ib]) - fmaxf(A1, ob1[ib]);
                float inter = fmaxf(iw, 0.0f) * fmaxf(ih, 0.0f);
                float denom = Aa + area[ib] - inter + 1e-6f;
                if (inter / denom > 0.6f) m |= (1ull << j);
            }
            sup[t] = m;
        }
        __syncthreads();
        if (t < NC) {
            unsigned long long kb = 0ULL;
            int base = cstart[t], mc = (int)ccnt[t];
            for (int w = 0; w < mc; ++w) {
                int i = clist[base + w];
                bool kp = keepf[i] && ((sup[i] & kb) == 0ULL);
                keepf[i] = kp ? 1 : 0;
                if (kp) kb |= (1ull << w);
            }
        }
    } else {
        __syncthreads();
        if (t < NC) {   // rare exact fallback
            int s0 = cstart[t], s1 = s0 + (int)ccnt[t];
            for (int a = s0; a < s1; ++a) {
                int ia = clist[a];
                if (!keepf[ia]) continue;
                float A0 = ob0[ia], A1 = ob1[ia], A2 = ob2[ia], A3 = ob3[ia];
                float Aa = area[ia];
                for (int b = a + 1; b < s1; ++b) {
                    int ib = clist[b];
                    if (!keepf[ib]) continue;
                    float iw = fminf(A2, ob2[ib]) - fmaxf(A0, ob0[ib]);
                    float ih = fminf(A3, ob3[ib]) - fmaxf(A1, ob1[ib]);
                    float inter = fmaxf(iw, 0.0f) * fmaxf(ih, 0.0f);
                    float denom = Aa + area[ib] - inter + 1e-6f;
                    if (inter / denom > 0.6f) keepf[ib] = 0;
                }
            }
        }
    }
    __syncthreads();

    // phase 8: prefix over keep flags -> output slots
    pfx[t] = (t < TOPK) ? (int)keepf[t] : 0;
    __syncthreads();
    for (int off = 1; off < 1024; off <<= 1) {
        int add = (t >= off) ? pfx[t - off] : 0;
        __syncthreads();
        pfx[t] += add;
        __syncthreads();
    }
    int total = pfx[1023];

    // phase 9: output (recompute decoded box for the <=100 kept)
    if (t < TOPK && keepf[t]) {
        int q = pfx[t] - 1;
        if (q < NPOST) {
            unsigned long long e = sbuf[t];
            unsigned li = ~(unsigned)(e & 0xFFFFFFFFu);
            unsigned k = li / NC;
            float a0 = anchors[k * 4 + 0], a1 = anchors[k * 4 + 1];
            float a2 = anchors[k * 4 + 2], a3 = anchors[k * 4 + 3];
            float r0 = breg[(n * 4 + 0) * HWQ + k];
            float r1 = breg[(n * 4 + 1) * HWQ + k];
            float r2 = breg[(n * 4 + 2) * HWQ + k];
            float r3 = breg[(n * 4 + 3) * HWQ + k];
            float aw = a2 - a0, ah = a3 - a1;
            float acx = a0 + 0.5f * aw, acy = a1 + 0.5f * ah;
            float dx = r0 / 10.0f, dy = r1 / 10.0f;
            float dw = fminf(r2 / 5.0f, 4.135166556742356f);
            float dh = fminf(r3 / 5.0f, 4.135166556742356f);
            float pcx = dx * aw + acx, pcy = dy * ah + acy;
            float pw = expf(dw) * aw, ph = expf(dh) * ah;
            float x1 = fminf(fmaxf(pcx - 0.5f * pw, 0.0f), 1216.0f);
            float y1 = fminf(fmaxf(pcy - 0.5f * ph, 0.0f), 800.0f);
            float x2 = fminf(fmaxf(pcx + 0.5f * pw, 0.0f), 1216.0f);
            float y2 = fminf(fmaxf(pcy + 0.5f * ph, 0.0f), 800.0f);
            float fused = unflipKey((unsigned)(e >> 32));
            outBoxes[(n * NPOST + q) * 4 + 0] = x1;
            outBoxes[(n * NPOST + q) * 4 + 1] = y1;
            outBoxes[(n * NPOST + q) * 4 + 2] = x2;
            outBoxes[(n * NPOST + q) * 4 + 3] = y2;
            outScores[n * NPOST + q] = sqrtf(fmaxf(fused, 0.0f));
            outLabels[n * NPOST + q] = (float)lbl[t];
        }
    }
    if (t < NPOST && t >= total) {
        outBoxes[(n * NPOST + t) * 4 + 0] = 0.0f;
        outBoxes[(n * NPOST + t) * 4 + 1] = 0.0f;
        outBoxes[(n * NPOST + t) * 4 + 2] = 0.0f;
        outBoxes[(n * NPOST + t) * 4 + 3] = 0.0f;
        outScores[n * NPOST + t] = 0.0f;
        outLabels[n * NPOST + t] = 0.0f;
    }
}

extern "C" void kernel_launch(void* const* d_in, const int* in_sizes, int n_in,
                              void* d_out, int out_size, void* d_ws, size_t ws_size,
                              hipStream_t stream) {
    const float* breg = (const float*)d_in[0];   // [8,4,100,152]
    const float* cent = (const float*)d_in[1];   // [8,1,100,152]
    // d_in[2] box_cls: unused by reference
    const float* dp   = (const float*)d_in[3];   // [8,15200,256]
    const float* anc  = (const float*)d_in[4];   // [15200,4]
    const float* pm   = (const float*)d_in[5];   // [80,256]

    char* ws = (char*)d_ws;
    size_t off_scores   = 0;                                   // 38,912,000
    size_t off_gh       = off_scores + (size_t)TOTAL * 4;      // 131,072
    size_t off_meta     = off_gh + (size_t)NIMG * 4096 * 4;    // 64 (pad 128)
    size_t off_nnz      = off_meta + 128;                      // 320 (pad 512)
    size_t off_tok      = off_nnz + 512;                       // 81,920
    size_t off_wt       = off_tok + (size_t)NC * NL * 4;       // 81,920
    size_t off_wavecnt  = off_wt + (size_t)NC * NL * 4;        // 152,000 (+64)
    size_t off_wavemask = off_wavecnt + (size_t)NWAVE * 4 + 64;// 1,216,000
    size_t needed       = off_wavemask + (size_t)NWAVE * 32;
    if (ws_size < needed) return;

    float*    scores  = (float*)(ws + off_scores);
    unsigned* gh      = (unsigned*)(ws + off_gh);
    unsigned* meta    = (unsigned*)(ws + off_meta);
    unsigned* nnz     = (unsigned*)(ws + off_nnz);
    unsigned* tok     = (unsigned*)(ws + off_tok);
    float*    wt      = (float*)(ws + off_wt);
    unsigned* wavecnt = (unsigned*)(ws + off_wavecnt);
    unsigned long long* wavemask = (unsigned long long*)(ws + off_wavemask);

    kinit<<<128, 256, 0, stream>>>(pm, nnz, tok, wt, gh);
    kscoreh<<<SBLK32, 512, 0, stream>>>(dp, cent, nnz, tok, wt, scores, gh);
    kfind1<<<NIMG, 256, 0, stream>>>(gh, meta);
    kcountM<<<CBLK, 256, 0, stream>>>((const float4*)scores, meta,
                                      wavecnt, wavemask);

    float* outBoxes  = (float*)d_out;                       // 8*100*4
    float* outScores = outBoxes + NIMG * NPOST * 4;         // 8*100
    float* outLabels = outScores + NIMG * NPOST;            // 8*100
    ktail<<<NIMG, 1024, 0, stream>>>(wavecnt, wavemask, scores, meta,
                                     anc, breg, outBoxes, outScores, outLabels);
}

// Round 13
// 188.415 us; speedup vs baseline: 1.1286x; 1.1243x over previous
//
#include <hip/hip_runtime.h>
#include <hip/hip_bf16.h>

#define NIMG 8
#define NC   80
#define NL   256
#define HWQ  15200
#define TOPK 1000
#define CAP  4096
#define SSORT 2048
#define NPOST 100
#define PERIMG (HWQ * NC)          // 1,216,000
#define TOTAL (NIMG * PERIMG)      // 9,728,000
#define SROW 32                    // rows per score block
#define SBLK32 (NIMG * HWQ / SROW) // 3800
#define PI4  (PERIMG / 4)          // 304,000 float4 per image
#define WPI  (PI4 / 64)            // 4750 waves per image
#define NWAVE (NIMG * WPI)         // 38,000
#define CBLK (TOTAL / 4 / 256)     // 9,500 blocks for count pass

__device__ __forceinline__ unsigned flipKey(float f) {
    unsigned u = __float_as_uint(f);
    return u ^ (((unsigned)((int)u >> 31)) | 0x80000000u);
}
__device__ __forceinline__ float unflipKey(unsigned k) {
    unsigned u = k ^ ((k & 0x80000000u) ? 0x80000000u : 0xFFFFFFFFu);
    return __uint_as_float(u);
}
__device__ __forceinline__ float sigmoidf(float x) {
    return 1.0f / (1.0f + expf(-x));
}

// ---- init: zero coarse histograms + extract (token, weight) lists ----
__global__ void __launch_bounds__(256)
kinit(const float* __restrict__ pm, unsigned* nnz, unsigned* tok, float* wt,
      unsigned* __restrict__ gh) {
    int g = blockIdx.x * 256 + threadIdx.x;
    if (g < NIMG * 4096) gh[g] = 0;            // 32768 threads == exact
    if (g < NC) {
        int c = g;
        int cnt = 0;
        for (int l = 0; l < NL; ++l) {
            float v = pm[c * NL + l];
            if (v != 0.0f) { tok[cnt * NC + c] = l; wt[cnt * NC + c] = v; cnt++; }
        }
        nnz[c] = cnt;
    }
}

// ---- fused scores + centerness + coarse 12-bit histogram (v3, round-10):
//      512 thr x 32 rows, float3 gather for consecutive tokens, 5-elem ILP ----
__global__ void __launch_bounds__(512)
kscoreh(const float* __restrict__ dp, const float* __restrict__ cent,
        const unsigned* __restrict__ nnz, const unsigned* __restrict__ tok,
        const float* __restrict__ wt, float* __restrict__ scores,
        unsigned* __restrict__ gh) {
    __shared__ unsigned h[4096];        // 16 KB
    __shared__ float sctr[SROW];
    int t = threadIdx.x;
    for (int i = t; i < 4096; i += 512) h[i] = 0;
    long long base = (long long)blockIdx.x * SROW;        // first global row
    if (t < SROW) sctr[t] = sigmoidf(cent[base + t]);     // once per row
    long long obase = base * NC;
    const float* dpb = dp + base * NL;

    int  rr[5], cc[5], mm[5];
    int  tk[5][3];
    float wv[5][3], xv[5][3];
#pragma unroll
    for (int j = 0; j < 5; ++j) {
        int o = t + j * 512;            // 0..2559 (32 rows x 80 classes)
        rr[j] = o / NC; cc[j] = o - rr[j] * NC;
        mm[j] = (int)nnz[cc[j]];
        int c = cc[j];
        tk[j][0] = (int)tok[c] & 255;           // clamp: safe vs stale ws
        tk[j][1] = (int)tok[NC + c] & 255;
        tk[j][2] = (int)tok[2 * NC + c] & 255;
        wv[j][0] = wt[c]; wv[j][1] = wt[NC + c]; wv[j][2] = wt[2 * NC + c];
    }
#pragma unroll
    for (int j = 0; j < 5; ++j) {       // all gathers issued before any exp
        const float* row = dpb + rr[j] * NL;
        if (tk[j][1] == tk[j][0] + 1 && tk[j][2] == tk[j][0] + 2) {
            float3 v3 = *(const float3*)(row + tk[j][0]);   // 1 VMEM, 12B
            xv[j][0] = v3.x; xv[j][1] = v3.y; xv[j][2] = v3.z;
        } else {
            xv[j][0] = row[tk[j][0]];
            xv[j][1] = row[tk[j][1]];
            xv[j][2] = row[tk[j][2]];
        }
    }
    __syncthreads();                    // sctr ready; hist zeroed
#pragma unroll
    for (int j = 0; j < 5; ++j) {
        float acc = 0.0f;
        if (mm[j] == 3) {               // identical arithmetic to prior rounds
            float s0 = sigmoidf(xv[j][0]);
            float s1 = sigmoidf(xv[j][1]);
            float s2 = sigmoidf(xv[j][2]);
            acc += s0 * wv[j][0]; acc += s1 * wv[j][1]; acc += s2 * wv[j][2];
        } else {
            const float* row = dpb + rr[j] * NL;
            for (int q = 0; q < mm[j]; ++q)
                acc += sigmoidf(row[tok[q * NC + cc[j]]]) * wt[q * NC + cc[j]];
        }
        float sc = (acc > 0.05f) ? acc * sctr[rr[j]] : -1.0f;
        scores[obase + t + j * 512] = sc;
        atomicAdd(&h[flipKey(sc) >> 20], 1u);
    }
    __syncthreads();
    int n = (int)(base / HWQ);          // 475 blocks per image exactly
    for (int i = t; i < 4096; i += 512)
        if (h[i]) atomicAdd(&gh[n * 4096 + i], h[i]);
}

// ---- find coarse bucket containing rank TOPK ----
__global__ void kfind1(const unsigned* __restrict__ gh, unsigned* meta) {
    __shared__ unsigned h[4096];
    __shared__ unsigned psum[256];
    int n = blockIdx.x;
    for (int i = threadIdx.x; i < 4096; i += 256) h[i] = gh[n * 4096 + i];
    __syncthreads();
    unsigned s = 0;
    for (int i = 0; i < 16; ++i) s += h[threadIdx.x * 16 + i];
    psum[threadIdx.x] = s;
    __syncthreads();
    if (threadIdx.x == 0) {
        unsigned cum = 0, above = 0; int B = 0; bool done = false;
        for (int seg = 255; seg >= 0 && !done; --seg) {
            if (cum + psum[seg] >= TOPK) {
                for (int b = seg * 16 + 15; b >= seg * 16; --b) {
                    if (cum + h[b] >= TOPK) { B = b; above = cum; done = true; break; }
                    cum += h[b];
                }
            } else cum += psum[seg];
        }
        meta[n] = (unsigned)B;
        meta[8 + n] = above;
    }
}

// ---- count pass with per-wave 256-bit selection masks (atomic-free) ----
__global__ void __launch_bounds__(256)
kcountM(const float4* __restrict__ scores4, const unsigned* __restrict__ meta,
        unsigned* __restrict__ wavecnt, unsigned long long* __restrict__ wavemask) {
    int i4 = blockIdx.x * 256 + threadIdx.x;
    int n = i4 / PI4;                 // wave-uniform (64 | PI4)
    unsigned B = meta[n];
    float4 v = scores4[i4];
    bool s0 = (flipKey(v.x) >> 20) >= B;
    bool s1 = (flipKey(v.y) >> 20) >= B;
    bool s2 = (flipKey(v.z) >> 20) >= B;
    bool s3 = (flipKey(v.w) >> 20) >= B;
    unsigned long long m0 = __ballot(s0);
    unsigned long long m1 = __ballot(s1);
    unsigned long long m2 = __ballot(s2);
    unsigned long long m3 = __ballot(s3);
    if ((threadIdx.x & 63) == 0) {
        int w = i4 >> 6;
        wavemask[(size_t)w * 4 + 0] = m0;
        wavemask[(size_t)w * 4 + 1] = m1;
        wavemask[(size_t)w * 4 + 2] = m2;
        wavemask[(size_t)w * 4 + 3] = m3;
        wavecnt[w] = (unsigned)(__popcll(m0) + __popcll(m1)
                              + __popcll(m2) + __popcll(m3));
    }
}

// ---- per-image: prefix over wave counts + sparse gather-write of cand ----
__global__ void __launch_bounds__(1024)
kscanW(const unsigned* __restrict__ wavecnt,
       const unsigned long long* __restrict__ wavemask,
       const float* __restrict__ scores,
       unsigned* __restrict__ cnt, unsigned long long* __restrict__ cand) {
    __shared__ unsigned ps[1024];
    int n = blockIdx.x, t = threadIdx.x;
    const unsigned* wc = wavecnt + n * WPI;
    int s0 = t * 5;                    // 5*1024 = 5120 >= 4750
    unsigned loc[5], vv[5]; unsigned sum = 0;
#pragma unroll
    for (int j = 0; j < 5; ++j) {
        int i = s0 + j;
        unsigned x = (i < WPI) ? wc[i] : 0u;
        vv[j] = x; loc[j] = sum; sum += x;
    }
    ps[t] = sum;
    __syncthreads();
    for (int off = 1; off < 1024; off <<= 1) {
        unsigned add = (t >= off) ? ps[t - off] : 0u;
        __syncthreads();
        ps[t] += add;
        __syncthreads();
    }
    unsigned excl = (t > 0) ? ps[t - 1] : 0u;
    if (t == 1023) cnt[n] = ps[1023];
    const float* sb = scores + (size_t)n * PERIMG;
    unsigned long long* cb = cand + (size_t)n * CAP;
#pragma unroll
    for (int j = 0; j < 5; ++j) {
        int wl = s0 + j;
        if (wl < WPI && vv[j]) {       // ~5% of waves non-empty
            unsigned off = excl + loc[j];
            const unsigned long long* mk = wavemask + ((size_t)(n * WPI + wl)) * 4;
#pragma unroll
            for (int e = 0; e < 4; ++e) {
                unsigned long long m = mk[e];
                while (m) {
                    int b = __ffsll(m) - 1; m &= m - 1;
                    int li = wl * 256 + b * 4 + e;
                    unsigned key = flipKey(sb[li]);
                    if (off < CAP)
                        cb[off] = ((unsigned long long)key << 32)
                                  | (unsigned)(~li);
                    off++;
                }
            }
        }
    }
}

// ---- fine threshold over compacted candidates + small exact sort ----
__global__ void __launch_bounds__(1024)
kfine(const unsigned long long* __restrict__ cand, const unsigned* __restrict__ cnt,
      const unsigned* __restrict__ meta, unsigned long long* __restrict__ sorted) {
    __shared__ unsigned h[4096];                 // 16 KB
    __shared__ unsigned long long sbuf[SSORT];   // 16 KB
    __shared__ unsigned psum[256];
    __shared__ unsigned selcnt;
    __shared__ unsigned Fbin;
    int n = blockIdx.x, t = threadIdx.x;
    int M = min(cnt[n], (unsigned)CAP);
    unsigned B = meta[n], above = meta[8 + n];
    const unsigned long long* cb = cand + (size_t)n * CAP;
    for (int i = t; i < 4096; i += 1024) h[i] = 0;
    sbuf[t] = 0ULL; sbuf[t + 1024] = 0ULL;
    if (t == 0) selcnt = 0;
    __syncthreads();
    for (int i = t; i < M; i += 1024) {
        unsigned key = (unsigned)(cb[i] >> 32);
        if ((key >> 20) == B) atomicAdd(&h[(key >> 8) & 0xFFFu], 1u);
    }
    __syncthreads();
    if (t < 256) {
        unsigned s = 0;
        for (int i = 0; i < 16; ++i) s += h[t * 16 + i];
        psum[t] = s;
    }
    __syncthreads();
    if (t == 0) {
        unsigned cum = above; int F = 0; bool done = false;
        for (int seg = 255; seg >= 0 && !done; --seg) {
            if (cum + psum[seg] >= TOPK) {
                for (int b = seg * 16 + 15; b >= seg * 16; --b) {
                    if (cum + h[b] >= TOPK) { F = b; done = true; break; }
                    cum += h[b];
                }
            } else cum += psum[seg];
        }
        Fbin = (unsigned)F;
    }
    __syncthreads();
    unsigned T24 = (B << 12) | Fbin;
    for (int i = t; i < M; i += 1024) {
        unsigned long long e = cb[i];
        unsigned key = (unsigned)(e >> 32);
        if ((key >> 8) >= T24) {
            unsigned p = atomicAdd(&selcnt, 1u);   // order irrelevant: full sort follows
            if (p < SSORT) sbuf[p] = e;
        }
    }
    __syncthreads();
    int s = (int)selcnt;
    int SN = (s <= 1024) ? 1024 : SSORT;
    for (int k = 2; k <= SN; k <<= 1) {
        for (int j = k >> 1; j > 0; j >>= 1) {
            for (int i = t; i < SN; i += 1024) {
                int l = i ^ j;
                if (l > i) {
                    unsigned long long a = sbuf[i], b = sbuf[l];
                    bool sw = ((i & k) == 0) ? (a < b) : (a > b);
                    if (sw) { sbuf[i] = b; sbuf[l] = a; }
                }
            }
            __syncthreads();
        }
    }
    if (t < TOPK) sorted[(n << 10) + t] = sbuf[t];
}

// ---- decode all 8x1000 candidates chip-wide ----
__global__ void __launch_bounds__(256)
kdecode(const unsigned long long* __restrict__ sorted,
        const float* __restrict__ anchors, const float* __restrict__ breg,
        float4* __restrict__ box4, float4* __restrict__ obx4,
        float* __restrict__ areag, unsigned* __restrict__ lblkeep) {
    int gid = blockIdx.x * 256 + threadIdx.x;
    if (gid >= NIMG * TOPK) return;
    int n = gid / TOPK, r = gid - n * TOPK;
    int o = (n << 10) + r;
    unsigned long long e = sorted[o];
    unsigned key = (unsigned)(e >> 32);
    bool real = key > 0x80000000u;       // masked value > 0
    unsigned li = ~(unsigned)(e & 0xFFFFFFFFu);
    unsigned k = li / NC, c = li - k * NC;
    int label = (int)c + 1;
    float x1 = 0, y1 = 0, x2 = 0, y2 = 0;
    bool val = false;
    if (real) {
        float a0 = anchors[k * 4 + 0], a1 = anchors[k * 4 + 1];
        float a2 = anchors[k * 4 + 2], a3 = anchors[k * 4 + 3];
        float r0 = breg[(n * 4 + 0) * HWQ + k];
        float r1 = breg[(n * 4 + 1) * HWQ + k];
        float r2 = breg[(n * 4 + 2) * HWQ + k];
        float r3 = breg[(n * 4 + 3) * HWQ + k];
        float aw = a2 - a0, ah = a3 - a1;
        float acx = a0 + 0.5f * aw, acy = a1 + 0.5f * ah;
        float dx = r0 / 10.0f, dy = r1 / 10.0f;
        float dw = fminf(r2 / 5.0f, 4.135166556742356f);
        float dh = fminf(r3 / 5.0f, 4.135166556742356f);
        float pcx = dx * aw + acx, pcy = dy * ah + acy;
        float pw = expf(dw) * aw, ph = expf(dh) * ah;
        x1 = fminf(fmaxf(pcx - 0.5f * pw, 0.0f), 1216.0f);
        y1 = fminf(fmaxf(pcy - 0.5f * ph, 0.0f), 800.0f);
        x2 = fminf(fmaxf(pcx + 0.5f * pw, 0.0f), 1216.0f);
        y2 = fminf(fmaxf(pcy + 0.5f * ph, 0.0f), 800.0f);
        val = (x2 - x1 > 0.0f) && (y2 - y1 > 0.0f);
    }
    box4[o] = make_float4(x1, y1, x2, y2);
    float off = (float)label * 10000.0f;   // replicate offset-then-round
    float o0 = x1 + off, o1 = y1 + off, o2 = x2 + off, o3 = y2 + off;
    obx4[o] = make_float4(o0, o1, o2, o3);
    areag[o] = (o2 - o0) * (o3 - o1);
    lblkeep[o] = (unsigned)(real ? label : 0) | ((val ? 1u : 0u) << 16);
}

// ---- per-image: class-decomposed bitmask NMS + output.
//      v2: within-class rank via per-class bitsets (<=16 popcounts)
//      instead of O(t) serial LDS scan; order-preserving by construction ----
__global__ void __launch_bounds__(1024)
knms2(const unsigned long long* __restrict__ sorted,
      const float4* __restrict__ obx4, const float* __restrict__ areag,
      const unsigned* __restrict__ lblkeep, const float4* __restrict__ box4,
      float* __restrict__ outBoxes, float* __restrict__ outScores,
      float* __restrict__ outLabels) {
    __shared__ float ob0[TOPK], ob1[TOPK], ob2[TOPK], ob3[TOPK], area[TOPK];
    __shared__ unsigned long long sup[TOPK];
    __shared__ unsigned long long cbits[NC * 16];   // 10,240 B class bitsets
    __shared__ unsigned short lbl[TOPK];
    __shared__ unsigned char  keepf[TOPK];
    __shared__ unsigned short wrank[TOPK];
    __shared__ unsigned short clist[TOPK];
    __shared__ unsigned short cstart[NC + 1];
    __shared__ unsigned ccnt[NC];
    __shared__ int pfx[1024];
    __shared__ int smax;

    int n = blockIdx.x, t = threadIdx.x;
    for (int i = t; i < NC * 16; i += 1024) cbits[i] = 0ULL;
    if (t == 0) smax = 0;
    if (t < TOPK) {
        int o = (n << 10) + t;
        float4 ob = obx4[o];
        ob0[t] = ob.x; ob1[t] = ob.y; ob2[t] = ob.z; ob3[t] = ob.w;
        area[t] = areag[o];
        unsigned lk = lblkeep[o];
        lbl[t] = (unsigned short)(lk & 0xFFFFu);
        keepf[t] = (unsigned char)(lk >> 16);
        sup[t] = 0ULL;
    }
    __syncthreads();

    // build class bitsets (bit position == sorted order)
    if (t < TOPK && lbl[t])
        atomicOr(&cbits[(lbl[t] - 1) * 16 + (t >> 6)], 1ull << (t & 63));
    __syncthreads();
    if (t < NC) {
        unsigned s = 0;
#pragma unroll
        for (int w = 0; w < 16; ++w) s += (unsigned)__popcll(cbits[t * 16 + w]);
        ccnt[t] = s;
    }
    __syncthreads();
    if (t < NC) atomicMax(&smax, (int)ccnt[t]);
    __syncthreads();
    if (t == 0) {
        unsigned s = 0;
        for (int c = 0; c < NC; ++c) { cstart[c] = (unsigned short)s; s += ccnt[c]; }
        cstart[NC] = (unsigned short)s;
    }
    __syncthreads();
    // rank = popcount of earlier bits in my class's bitset
    if (t < TOPK && lbl[t]) {
        int my = lbl[t] - 1;
        int w = 0;
        int hi = t >> 6;
        for (int q = 0; q < hi; ++q) w += (int)__popcll(cbits[my * 16 + q]);
        w += (int)__popcll(cbits[my * 16 + hi] & ((1ull << (t & 63)) - 1ull));
        wrank[t] = (unsigned short)w;
        clist[cstart[my] + w] = (unsigned short)t;
    }
    __syncthreads();

    if (smax <= 64) {
        if (t < TOPK && lbl[t]) {
            int base = cstart[lbl[t] - 1];
            int w = wrank[t];
            float A0 = ob0[t], A1 = ob1[t], A2 = ob2[t], A3 = ob3[t], Aa = area[t];
            unsigned long long m = 0ULL;
            for (int j = 0; j < w; ++j) {
                int ib = clist[base + j];
                float iw = fminf(A2, ob2[ib]) - fmaxf(A0, ob0[ib]);
                float ih = fminf(A3, ob3[ib]) - fmaxf(A1, ob1[ib]);
                float inter = fmaxf(iw, 0.0f) * fmaxf(ih, 0.0f);
                float denom = Aa + area[ib] - inter + 1e-6f;
                if (inter / denom > 0.6f) m |= (1ull << j);
            }
            sup[t] = m;
        }
        __syncthreads();
        if (t < NC) {
            unsigned long long kb = 0ULL;
            int base = cstart[t], mc = (int)ccnt[t];
            for (int w = 0; w < mc; ++w) {
                int i = clist[base + w];
                bool kp = keepf[i] && ((sup[i] & kb) == 0ULL);
                keepf[i] = kp ? 1 : 0;
                if (kp) kb |= (1ull << w);
            }
        }
    } else {
        __syncthreads();
        if (t < NC) {   // rare exact fallback
            int s0 = cstart[t], s1 = s0 + (int)ccnt[t];
            for (int a = s0; a < s1; ++a) {
                int ia = clist[a];
                if (!keepf[ia]) continue;
                float A0 = ob0[ia], A1 = ob1[ia], A2 = ob2[ia], A3 = ob3[ia];
                float Aa = area[ia];
                for (int b = a + 1; b < s1; ++b) {
                    int ib = clist[b];
                    if (!keepf[ib]) continue;
                    float iw = fminf(A2, ob2[ib]) - fmaxf(A0, ob0[ib]);
                    float ih = fminf(A3, ob3[ib]) - fmaxf(A1, ob1[ib]);
                    float inter = fmaxf(iw, 0.0f) * fmaxf(ih, 0.0f);
                    float denom = Aa + area[ib] - inter + 1e-6f;
                    if (inter / denom > 0.6f) keepf[ib] = 0;
                }
            }
        }
    }
    __syncthreads();

    pfx[t] = (t < TOPK) ? (int)keepf[t] : 0;
    __syncthreads();
    for (int off = 1; off < 1024; off <<= 1) {
        int add = (t >= off) ? pfx[t - off] : 0;
        __syncthreads();
        pfx[t] += add;
        __syncthreads();
    }
    int total = pfx[1023];

    if (t < TOPK && keepf[t]) {
        int q = pfx[t] - 1;
        if (q < NPOST) {
            int o = (n << 10) + t;
            float4 b = box4[o];
            float fused = unflipKey((unsigned)(sorted[o] >> 32));
            outBoxes[(n * NPOST + q) * 4 + 0] = b.x;
            outBoxes[(n * NPOST + q) * 4 + 1] = b.y;
            outBoxes[(n * NPOST + q) * 4 + 2] = b.z;
            outBoxes[(n * NPOST + q) * 4 + 3] = b.w;
            outScores[n * NPOST + q] = sqrtf(fmaxf(fused, 0.0f));
            outLabels[n * NPOST + q] = (float)lbl[t];
        }
    }
    if (t < NPOST && t >= total) {
        outBoxes[(n * NPOST + t) * 4 + 0] = 0.0f;
        outBoxes[(n * NPOST + t) * 4 + 1] = 0.0f;
        outBoxes[(n * NPOST + t) * 4 + 2] = 0.0f;
        outBoxes[(n * NPOST + t) * 4 + 3] = 0.0f;
        outScores[n * NPOST + t] = 0.0f;
        outLabels[n * NPOST + t] = 0.0f;
    }
}

extern "C" void kernel_launch(void* const* d_in, const int* in_sizes, int n_in,
                              void* d_out, int out_size, void* d_ws, size_t ws_size,
                              hipStream_t stream) {
    const float* breg = (const float*)d_in[0];   // [8,4,100,152]
    const float* cent = (const float*)d_in[1];   // [8,1,100,152]
    // d_in[2] box_cls: unused by reference
    const float* dp   = (const float*)d_in[3];   // [8,15200,256]
    const float* anc  = (const float*)d_in[4];   // [15200,4]
    const float* pm   = (const float*)d_in[5];   // [80,256]

    char* ws = (char*)d_ws;
    size_t off_scores   = 0;                                   // 38,912,000
    size_t off_gh       = off_scores + (size_t)TOTAL * 4;      // 131,072
    size_t off_cnt      = off_gh + (size_t)NIMG * 4096 * 4;    // 32 (pad 128)
    size_t off_meta     = off_cnt + 128;                       // 64 (pad 128)
    size_t off_cand     = off_meta + 128;                      // 262,144
    size_t off_nnz      = off_cand + (size_t)NIMG * CAP * 8;   // 320 (pad 512)
    size_t off_tok      = off_nnz + 512;                       // 81,920
    size_t off_wt       = off_tok + (size_t)NC * NL * 4;       // 81,920
    size_t off_wavecnt  = off_wt + (size_t)NC * NL * 4;        // 152,000 (+64)
    size_t off_wavemask = off_wavecnt + (size_t)NWAVE * 4 + 64;// 1,216,000
    size_t needed       = off_wavemask + (size_t)NWAVE * 32;
    if (ws_size < needed) return;

    // post-compaction arrays alias the scores region (scores dead after
    // compaction; rewritten from scratch by kscoreh each replay)
    size_t off_sorted = off_scores;                            // 65,536
    size_t off_box4   = off_sorted + (size_t)NIMG * 1024 * 8;  // 131,072
    size_t off_obx4   = off_box4 + (size_t)NIMG * 1024 * 16;   // 131,072
    size_t off_area   = off_obx4 + (size_t)NIMG * 1024 * 16;   // 32,768
    size_t off_lblk   = off_area + (size_t)NIMG * 1024 * 4;    // 32,768

    float*    scores  = (float*)(ws + off_scores);
    unsigned* gh      = (unsigned*)(ws + off_gh);
    unsigned* cnt     = (unsigned*)(ws + off_cnt);
    unsigned* meta    = (unsigned*)(ws + off_meta);
    unsigned long long* cand = (unsigned long long*)(ws + off_cand);
    unsigned* nnz     = (unsigned*)(ws + off_nnz);
    unsigned* tok     = (unsigned*)(ws + off_tok);
    float*    wt      = (float*)(ws + off_wt);
    unsigned* wavecnt = (unsigned*)(ws + off_wavecnt);
    unsigned long long* wavemask = (unsigned long long*)(ws + off_wavemask);
    unsigned long long* sorted = (unsigned long long*)(ws + off_sorted);
    float4*   box4    = (float4*)(ws + off_box4);
    float4*   obx4    = (float4*)(ws + off_obx4);
    float*    areag   = (float*)(ws + off_area);
    unsigned* lblkeep = (unsigned*)(ws + off_lblk);

    kinit<<<128, 256, 0, stream>>>(pm, nnz, tok, wt, gh);
    kscoreh<<<SBLK32, 512, 0, stream>>>(dp, cent, nnz, tok, wt, scores, gh);
    kfind1<<<NIMG, 256, 0, stream>>>(gh, meta);
    kcountM<<<CBLK, 256, 0, stream>>>((const float4*)scores, meta,
                                      wavecnt, wavemask);
    kscanW<<<NIMG, 1024, 0, stream>>>(wavecnt, wavemask, scores, cnt, cand);
    kfine<<<NIMG, 1024, 0, stream>>>(cand, cnt, meta, sorted);
    kdecode<<<(NIMG * TOPK + 255) / 256, 256, 0, stream>>>(sorted, anc, breg,
                                                           box4, obx4, areag, lblkeep);

    float* outBoxes  = (float*)d_out;                       // 8*100*4
    float* outScores = outBoxes + NIMG * NPOST * 4;         // 8*100
    float* outLabels = outScores + NIMG * NPOST;            // 8*100
    knms2<<<NIMG, 1024, 0, stream>>>(sorted, obx4, areag, lblkeep, box4,
                                     outBoxes, outScores, outLabels);
}

// Round 14
// 186.535 us; speedup vs baseline: 1.1400x; 1.0101x over previous
//
#include <hip/hip_runtime.h>
#include <hip/hip_bf16.h>

#define NIMG 8
#define NC   80
#define NL   256
#define HWQ  15200
#define TOPK 1000
#define CAP  4096
#define SSORT 2048
#define NPOST 100
#define PERIMG (HWQ * NC)          // 1,216,000
#define TOTAL (NIMG * PERIMG)      // 9,728,000
#define SROW 32                    // rows per score block
#define SBLK32 (NIMG * HWQ / SROW) // 3800
#define PI4  (PERIMG / 4)          // 304,000 float4 per image
#define WPI  (PI4 / 64)            // 4750 waves per image
#define NWAVE (NIMG * WPI)         // 38,000
#define CBLK (TOTAL / 4 / 256)     // 9,500 blocks for count pass

__device__ __forceinline__ unsigned flipKey(float f) {
    unsigned u = __float_as_uint(f);
    return u ^ (((unsigned)((int)u >> 31)) | 0x80000000u);
}
__device__ __forceinline__ float unflipKey(unsigned k) {
    unsigned u = k ^ ((k & 0x80000000u) ? 0x80000000u : 0xFFFFFFFFu);
    return __uint_as_float(u);
}
__device__ __forceinline__ float sigmoidf(float x) {
    return 1.0f / (1.0f + expf(-x));
}

// ---- init: zero coarse histograms + extract (token, weight) lists ----
__global__ void __launch_bounds__(256)
kinit(const float* __restrict__ pm, unsigned* nnz, unsigned* tok, float* wt,
      unsigned* __restrict__ gh) {
    int g = blockIdx.x * 256 + threadIdx.x;
    if (g < NIMG * 4096) gh[g] = 0;            // 32768 threads == exact
    if (g < NC) {
        int c = g;
        int cnt = 0;
        for (int l = 0; l < NL; ++l) {
            float v = pm[c * NL + l];
            if (v != 0.0f) { tok[cnt * NC + c] = l; wt[cnt * NC + c] = v; cnt++; }
        }
        nnz[c] = cnt;
    }
}

// ---- fused scores + centerness + coarse 12-bit histogram (v3, round-10) ----
__global__ void __launch_bounds__(512)
kscoreh(const float* __restrict__ dp, const float* __restrict__ cent,
        const unsigned* __restrict__ nnz, const unsigned* __restrict__ tok,
        const float* __restrict__ wt, float* __restrict__ scores,
        unsigned* __restrict__ gh) {
    __shared__ unsigned h[4096];        // 16 KB
    __shared__ float sctr[SROW];
    int t = threadIdx.x;
    for (int i = t; i < 4096; i += 512) h[i] = 0;
    long long base = (long long)blockIdx.x * SROW;        // first global row
    if (t < SROW) sctr[t] = sigmoidf(cent[base + t]);     // once per row
    long long obase = base * NC;
    const float* dpb = dp + base * NL;

    int  rr[5], cc[5], mm[5];
    int  tk[5][3];
    float wv[5][3], xv[5][3];
#pragma unroll
    for (int j = 0; j < 5; ++j) {
        int o = t + j * 512;            // 0..2559 (32 rows x 80 classes)
        rr[j] = o / NC; cc[j] = o - rr[j] * NC;
        mm[j] = (int)nnz[cc[j]];
        int c = cc[j];
        tk[j][0] = (int)tok[c] & 255;           // clamp: safe vs stale ws
        tk[j][1] = (int)tok[NC + c] & 255;
        tk[j][2] = (int)tok[2 * NC + c] & 255;
        wv[j][0] = wt[c]; wv[j][1] = wt[NC + c]; wv[j][2] = wt[2 * NC + c];
    }
#pragma unroll
    for (int j = 0; j < 5; ++j) {       // all gathers issued before any exp
        const float* row = dpb + rr[j] * NL;
        if (tk[j][1] == tk[j][0] + 1 && tk[j][2] == tk[j][0] + 2) {
            float3 v3 = *(const float3*)(row + tk[j][0]);   // 1 VMEM, 12B
            xv[j][0] = v3.x; xv[j][1] = v3.y; xv[j][2] = v3.z;
        } else {
            xv[j][0] = row[tk[j][0]];
            xv[j][1] = row[tk[j][1]];
            xv[j][2] = row[tk[j][2]];
        }
    }
    __syncthreads();                    // sctr ready; hist zeroed
#pragma unroll
    for (int j = 0; j < 5; ++j) {
        float acc = 0.0f;
        if (mm[j] == 3) {               // identical arithmetic to prior rounds
            float s0 = sigmoidf(xv[j][0]);
            float s1 = sigmoidf(xv[j][1]);
            float s2 = sigmoidf(xv[j][2]);
            acc += s0 * wv[j][0]; acc += s1 * wv[j][1]; acc += s2 * wv[j][2];
        } else {
            const float* row = dpb + rr[j] * NL;
            for (int q = 0; q < mm[j]; ++q)
                acc += sigmoidf(row[tok[q * NC + cc[j]]]) * wt[q * NC + cc[j]];
        }
        float sc = (acc > 0.05f) ? acc * sctr[rr[j]] : -1.0f;
        scores[obase + t + j * 512] = sc;
        atomicAdd(&h[flipKey(sc) >> 20], 1u);
    }
    __syncthreads();
    int n = (int)(base / HWQ);          // 475 blocks per image exactly
    for (int i = t; i < 4096; i += 512)
        if (h[i]) atomicAdd(&gh[n * 4096 + i], h[i]);
}

// ---- find coarse bucket containing rank TOPK ----
__global__ void kfind1(const unsigned* __restrict__ gh, unsigned* meta) {
    __shared__ unsigned h[4096];
    __shared__ unsigned psum[256];
    int n = blockIdx.x;
    for (int i = threadIdx.x; i < 4096; i += 256) h[i] = gh[n * 4096 + i];
    __syncthreads();
    unsigned s = 0;
    for (int i = 0; i < 16; ++i) s += h[threadIdx.x * 16 + i];
    psum[threadIdx.x] = s;
    __syncthreads();
    if (threadIdx.x == 0) {
        unsigned cum = 0, above = 0; int B = 0; bool done = false;
        for (int seg = 255; seg >= 0 && !done; --seg) {
            if (cum + psum[seg] >= TOPK) {
                for (int b = seg * 16 + 15; b >= seg * 16; --b) {
                    if (cum + h[b] >= TOPK) { B = b; above = cum; done = true; break; }
                    cum += h[b];
                }
            } else cum += psum[seg];
        }
        meta[n] = (unsigned)B;
        meta[8 + n] = above;
    }
}

// ---- count pass with per-wave 256-bit selection masks (atomic-free) ----
__global__ void __launch_bounds__(256)
kcountM(const float4* __restrict__ scores4, const unsigned* __restrict__ meta,
        unsigned* __restrict__ wavecnt, unsigned long long* __restrict__ wavemask) {
    int i4 = blockIdx.x * 256 + threadIdx.x;
    int n = i4 / PI4;                 // wave-uniform (64 | PI4)
    unsigned B = meta[n];
    float4 v = scores4[i4];
    bool s0 = (flipKey(v.x) >> 20) >= B;
    bool s1 = (flipKey(v.y) >> 20) >= B;
    bool s2 = (flipKey(v.z) >> 20) >= B;
    bool s3 = (flipKey(v.w) >> 20) >= B;
    unsigned long long m0 = __ballot(s0);
    unsigned long long m1 = __ballot(s1);
    unsigned long long m2 = __ballot(s2);
    unsigned long long m3 = __ballot(s3);
    if ((threadIdx.x & 63) == 0) {
        int w = i4 >> 6;
        wavemask[(size_t)w * 4 + 0] = m0;
        wavemask[(size_t)w * 4 + 1] = m1;
        wavemask[(size_t)w * 4 + 2] = m2;
        wavemask[(size_t)w * 4 + 3] = m3;
        wavecnt[w] = (unsigned)(__popcll(m0) + __popcll(m1)
                              + __popcll(m2) + __popcll(m3));
    }
}

// ---- merged kscanW+kfine: prefix over wave counts, gather selected
//      candidates DIRECTLY into LDS (common path: total <= SSORT), sort,
//      emit exact top-1000.  Fallback (total > SSORT): gather to global
//      cand + fine-threshold select (old kfine logic, inlined). ----
__global__ void __launch_bounds__(1024)
kgather(const unsigned* __restrict__ wavecnt,
        const unsigned long long* __restrict__ wavemask,
        const float* __restrict__ scores, const unsigned* __restrict__ meta,
        unsigned long long* __restrict__ cand,
        unsigned long long* __restrict__ sorted) {
    __shared__ unsigned ps[1024];                // 4 KB
    __shared__ unsigned long long sbuf[SSORT];   // 16 KB
    __shared__ unsigned h[4096];                 // 16 KB (fallback only)
    __shared__ unsigned psum[256];
    __shared__ unsigned selcnt, Fbin;
    int n = blockIdx.x, t = threadIdx.x;
    const unsigned* wc = wavecnt + n * WPI;
    const unsigned long long* wm = wavemask + (size_t)n * WPI * 4;
    const float* sb = scores + (size_t)n * PERIMG;
    sbuf[t] = 0ULL; sbuf[t + 1024] = 0ULL;

    // exclusive prefix over the image's 4750 wave counts
    int s0 = t * 5;                    // 5*1024 = 5120 >= 4750
    unsigned loc[5], vv[5]; unsigned sum = 0;
#pragma unroll
    for (int j = 0; j < 5; ++j) {
        int i = s0 + j;
        unsigned x = (i < WPI) ? wc[i] : 0u;
        vv[j] = x; loc[j] = sum; sum += x;
    }
    ps[t] = sum;
    __syncthreads();
    for (int off = 1; off < 1024; off <<= 1) {
        unsigned add = (t >= off) ? ps[t - off] : 0u;
        __syncthreads();
        ps[t] += add;
        __syncthreads();
    }
    unsigned excl = (t > 0) ? ps[t - 1] : 0u;
    unsigned total = ps[1023];         // uniform across block
    int nsel;

    if (total <= SSORT) {
        // common path: gather straight into the LDS sort buffer
#pragma unroll
        for (int j = 0; j < 5; ++j) {
            int wl = s0 + j;
            if (wl < WPI && vv[j]) {
                unsigned off = excl + loc[j];
                const unsigned long long* mk = wm + (size_t)wl * 4;
#pragma unroll
                for (int e = 0; e < 4; ++e) {
                    unsigned long long m = mk[e];
                    while (m) {
                        int b = __ffsll(m) - 1; m &= m - 1;
                        int li = wl * 256 + b * 4 + e;
                        unsigned key = flipKey(sb[li]);
                        sbuf[off++] = ((unsigned long long)key << 32)
                                      | (unsigned)(~li);
                    }
                }
            }
        }
        nsel = (int)total;
        __syncthreads();
    } else {
        // fallback: gather to global cand, then fine-threshold select
        unsigned long long* cb = cand + (size_t)n * CAP;
#pragma unroll
        for (int j = 0; j < 5; ++j) {
            int wl = s0 + j;
            if (wl < WPI && vv[j]) {
                unsigned off = excl + loc[j];
                const unsigned long long* mk = wm + (size_t)wl * 4;
#pragma unroll
                for (int e = 0; e < 4; ++e) {
                    unsigned long long m = mk[e];
                    while (m) {
                        int b = __ffsll(m) - 1; m &= m - 1;
                        int li = wl * 256 + b * 4 + e;
                        unsigned key = flipKey(sb[li]);
                        if (off < CAP)
                            cb[off] = ((unsigned long long)key << 32)
                                      | (unsigned)(~li);
                        off++;
                    }
                }
            }
        }
        for (int i = t; i < 4096; i += 1024) h[i] = 0;
        if (t == 0) selcnt = 0;
        __syncthreads();
        int M = min((int)total, CAP);
        unsigned B = meta[n], above = meta[8 + n];
        for (int i = t; i < M; i += 1024) {
            unsigned key = (unsigned)(cb[i] >> 32);
            if ((key >> 20) == B) atomicAdd(&h[(key >> 8) & 0xFFFu], 1u);
        }
        __syncthreads();
        if (t < 256) {
            unsigned s = 0;
            for (int i = 0; i < 16; ++i) s += h[t * 16 + i];
            psum[t] = s;
        }
        __syncthreads();
        if (t == 0) {
            unsigned cum = above; int F = 0; bool done = false;
            for (int seg = 255; seg >= 0 && !done; --seg) {
                if (cum + psum[seg] >= TOPK) {
                    for (int b = seg * 16 + 15; b >= seg * 16; --b) {
                        if (cum + h[b] >= TOPK) { F = b; done = true; break; }
                        cum += h[b];
                    }
                } else cum += psum[seg];
            }
            Fbin = (unsigned)F;
        }
        __syncthreads();
        unsigned T24 = (meta[n] << 12) | Fbin;
        for (int i = t; i < M; i += 1024) {
            unsigned long long e = cb[i];
            unsigned key = (unsigned)(e >> 32);
            if ((key >> 8) >= T24) {
                unsigned p = atomicAdd(&selcnt, 1u);
                if (p < SSORT) sbuf[p] = e;
            }
        }
        __syncthreads();
        nsel = (int)selcnt;
    }

    // bitonic sort descending on unique (key<<32)|~idx
    int SN = (nsel <= 1024) ? 1024 : SSORT;
    for (int k = 2; k <= SN; k <<= 1) {
        for (int j = k >> 1; j > 0; j >>= 1) {
            for (int i = t; i < SN; i += 1024) {
                int l = i ^ j;
                if (l > i) {
                    unsigned long long a = sbuf[i], b = sbuf[l];
                    bool sw = ((i & k) == 0) ? (a < b) : (a > b);
                    if (sw) { sbuf[i] = b; sbuf[l] = a; }
                }
            }
            __syncthreads();
        }
    }
    if (t < TOPK) sorted[(n << 10) + t] = sbuf[t];
}

// ---- decode all 8x1000 candidates chip-wide ----
__global__ void __launch_bounds__(256)
kdecode(const unsigned long long* __restrict__ sorted,
        const float* __restrict__ anchors, const float* __restrict__ breg,
        float4* __restrict__ box4, float4* __restrict__ obx4,
        float* __restrict__ areag, unsigned* __restrict__ lblkeep) {
    int gid = blockIdx.x * 256 + threadIdx.x;
    if (gid >= NIMG * TOPK) return;
    int n = gid / TOPK, r = gid - n * TOPK;
    int o = (n << 10) + r;
    unsigned long long e = sorted[o];
    unsigned key = (unsigned)(e >> 32);
    bool real = key > 0x80000000u;       // masked value > 0
    unsigned li = ~(unsigned)(e & 0xFFFFFFFFu);
    unsigned k = li / NC, c = li - k * NC;
    int label = (int)c + 1;
    float x1 = 0, y1 = 0, x2 = 0, y2 = 0;
    bool val = false;
    if (real) {
        float a0 = anchors[k * 4 + 0], a1 = anchors[k * 4 + 1];
        float a2 = anchors[k * 4 + 2], a3 = anchors[k * 4 + 3];
        float r0 = breg[(n * 4 + 0) * HWQ + k];
        float r1 = breg[(n * 4 + 1) * HWQ + k];
        float r2 = breg[(n * 4 + 2) * HWQ + k];
        float r3 = breg[(n * 4 + 3) * HWQ + k];
        float aw = a2 - a0, ah = a3 - a1;
        float acx = a0 + 0.5f * aw, acy = a1 + 0.5f * ah;
        float dx = r0 / 10.0f, dy = r1 / 10.0f;
        float dw = fminf(r2 / 5.0f, 4.135166556742356f);
        float dh = fminf(r3 / 5.0f, 4.135166556742356f);
        float pcx = dx * aw + acx, pcy = dy * ah + acy;
        float pw = expf(dw) * aw, ph = expf(dh) * ah;
        x1 = fminf(fmaxf(pcx - 0.5f * pw, 0.0f), 1216.0f);
        y1 = fminf(fmaxf(pcy - 0.5f * ph, 0.0f), 800.0f);
        x2 = fminf(fmaxf(pcx + 0.5f * pw, 0.0f), 1216.0f);
        y2 = fminf(fmaxf(pcy + 0.5f * ph, 0.0f), 800.0f);
        val = (x2 - x1 > 0.0f) && (y2 - y1 > 0.0f);
    }
    box4[o] = make_float4(x1, y1, x2, y2);
    float off = (float)label * 10000.0f;   // replicate offset-then-round
    float o0 = x1 + off, o1 = y1 + off, o2 = x2 + off, o3 = y2 + off;
    obx4[o] = make_float4(o0, o1, o2, o3);
    areag[o] = (o2 - o0) * (o3 - o1);
    lblkeep[o] = (unsigned)(real ? label : 0) | ((val ? 1u : 0u) << 16);
}

// ---- per-image: class-decomposed bitmask NMS + output (bitset ranks) ----
__global__ void __launch_bounds__(1024)
knms2(const unsigned long long* __restrict__ sorted,
      const float4* __restrict__ obx4, const float* __restrict__ areag,
      const unsigned* __restrict__ lblkeep, const float4* __restrict__ box4,
      float* __restrict__ outBoxes, float* __restrict__ outScores,
      float* __restrict__ outLabels) {
    __shared__ float ob0[TOPK], ob1[TOPK], ob2[TOPK], ob3[TOPK], area[TOPK];
    __shared__ unsigned long long sup[TOPK];
    __shared__ unsigned long long cbits[NC * 16];   // 10,240 B class bitsets
    __shared__ unsigned short lbl[TOPK];
    __shared__ unsigned char  keepf[TOPK];
    __shared__ unsigned short wrank[TOPK];
    __shared__ unsigned short clist[TOPK];
    __shared__ unsigned short cstart[NC + 1];
    __shared__ unsigned ccnt[NC];
    __shared__ int pfx[1024];
    __shared__ int smax;

    int n = blockIdx.x, t = threadIdx.x;
    for (int i = t; i < NC * 16; i += 1024) cbits[i] = 0ULL;
    if (t == 0) smax = 0;
    if (t < TOPK) {
        int o = (n << 10) + t;
        float4 ob = obx4[o];
        ob0[t] = ob.x; ob1[t] = ob.y; ob2[t] = ob.z; ob3[t] = ob.w;
        area[t] = areag[o];
        unsigned lk = lblkeep[o];
        lbl[t] = (unsigned short)(lk & 0xFFFFu);
        keepf[t] = (unsigned char)(lk >> 16);
        sup[t] = 0ULL;
    }
    __syncthreads();

    // build class bitsets (bit position == sorted order)
    if (t < TOPK && lbl[t])
        atomicOr(&cbits[(lbl[t] - 1) * 16 + (t >> 6)], 1ull << (t & 63));
    __syncthreads();
    if (t < NC) {
        unsigned s = 0;
#pragma unroll
        for (int w = 0; w < 16; ++w) s += (unsigned)__popcll(cbits[t * 16 + w]);
        ccnt[t] = s;
    }
    __syncthreads();
    if (t < NC) atomicMax(&smax, (int)ccnt[t]);
    __syncthreads();
    if (t == 0) {
        unsigned s = 0;
        for (int c = 0; c < NC; ++c) { cstart[c] = (unsigned short)s; s += ccnt[c]; }
        cstart[NC] = (unsigned short)s;
    }
    __syncthreads();
    // rank = popcount of earlier bits in my class's bitset
    if (t < TOPK && lbl[t]) {
        int my = lbl[t] - 1;
        int w = 0;
        int hi = t >> 6;
        for (int q = 0; q < hi; ++q) w += (int)__popcll(cbits[my * 16 + q]);
        w += (int)__popcll(cbits[my * 16 + hi] & ((1ull << (t & 63)) - 1ull));
        wrank[t] = (unsigned short)w;
        clist[cstart[my] + w] = (unsigned short)t;
    }
    __syncthreads();

    if (smax <= 64) {
        if (t < TOPK && lbl[t]) {
            int base = cstart[lbl[t] - 1];
            int w = wrank[t];
            float A0 = ob0[t], A1 = ob1[t], A2 = ob2[t], A3 = ob3[t], Aa = area[t];
            unsigned long long m = 0ULL;
            for (int j = 0; j < w; ++j) {
                int ib = clist[base + j];
                float iw = fminf(A2, ob2[ib]) - fmaxf(A0, ob0[ib]);
                float ih = fminf(A3, ob3[ib]) - fmaxf(A1, ob1[ib]);
                float inter = fmaxf(iw, 0.0f) * fmaxf(ih, 0.0f);
                float denom = Aa + area[ib] - inter + 1e-6f;
                if (inter / denom > 0.6f) m |= (1ull << j);
            }
            sup[t] = m;
        }
        __syncthreads();
        if (t < NC) {
            unsigned long long kb = 0ULL;
            int base = cstart[t], mc = (int)ccnt[t];
            for (int w = 0; w < mc; ++w) {
                int i = clist[base + w];
                bool kp = keepf[i] && ((sup[i] & kb) == 0ULL);
                keepf[i] = kp ? 1 : 0;
                if (kp) kb |= (1ull << w);
            }
        }
    } else {
        __syncthreads();
        if (t < NC) {   // rare exact fallback
            int s0 = cstart[t], s1 = s0 + (int)ccnt[t];
            for (int a = s0; a < s1; ++a) {
                int ia = clist[a];
                if (!keepf[ia]) continue;
                float A0 = ob0[ia], A1 = ob1[ia], A2 = ob2[ia], A3 = ob3[ia];
                float Aa = area[ia];
                for (int b = a + 1; b < s1; ++b) {
                    int ib = clist[b];
                    if (!keepf[ib]) continue;
                    float iw = fminf(A2, ob2[ib]) - fmaxf(A0, ob0[ib]);
                    float ih = fminf(A3, ob3[ib]) - fmaxf(A1, ob1[ib]);
                    float inter = fmaxf(iw, 0.0f) * fmaxf(ih, 0.0f);
                    float denom = Aa + area[ib] - inter + 1e-6f;
                    if (inter / denom > 0.6f) keepf[ib] = 0;
                }
            }
        }
    }
    __syncthreads();

    pfx[t] = (t < TOPK) ? (int)keepf[t] : 0;
    __syncthreads();
    for (int off = 1; off < 1024; off <<= 1) {
        int add = (t >= off) ? pfx[t - off] : 0;
        __syncthreads();
        pfx[t] += add;
        __syncthreads();
    }
    int total = pfx[1023];

    if (t < TOPK && keepf[t]) {
        int q = pfx[t] - 1;
        if (q < NPOST) {
            int o = (n << 10) + t;
            float4 b = box4[o];
            float fused = unflipKey((unsigned)(sorted[o] >> 32));
            outBoxes[(n * NPOST + q) * 4 + 0] = b.x;
            outBoxes[(n * NPOST + q) * 4 + 1] = b.y;
            outBoxes[(n * NPOST + q) * 4 + 2] = b.z;
            outBoxes[(n * NPOST + q) * 4 + 3] = b.w;
            outScores[n * NPOST + q] = sqrtf(fmaxf(fused, 0.0f));
            outLabels[n * NPOST + q] = (float)lbl[t];
        }
    }
    if (t < NPOST && t >= total) {
        outBoxes[(n * NPOST + t) * 4 + 0] = 0.0f;
        outBoxes[(n * NPOST + t) * 4 + 1] = 0.0f;
        outBoxes[(n * NPOST + t) * 4 + 2] = 0.0f;
        outBoxes[(n * NPOST + t) * 4 + 3] = 0.0f;
        outScores[n * NPOST + t] = 0.0f;
        outLabels[n * NPOST + t] = 0.0f;
    }
}

extern "C" void kernel_launch(void* const* d_in, const int* in_sizes, int n_in,
                              void* d_out, int out_size, void* d_ws, size_t ws_size,
                              hipStream_t stream) {
    const float* breg = (const float*)d_in[0];   // [8,4,100,152]
    const float* cent = (const float*)d_in[1];   // [8,1,100,152]
    // d_in[2] box_cls: unused by reference
    const float* dp   = (const float*)d_in[3];   // [8,15200,256]
    const float* anc  = (const float*)d_in[4];   // [15200,4]
    const float* pm   = (const float*)d_in[5];   // [80,256]

    char* ws = (char*)d_ws;
    size_t off_scores   = 0;                                   // 38,912,000
    size_t off_gh       = off_scores + (size_t)TOTAL * 4;      // 131,072
    size_t off_meta     = off_gh + (size_t)NIMG * 4096 * 4;    // 64 (pad 128)
    size_t off_cand     = off_meta + 128;                      // 262,144
    size_t off_nnz      = off_cand + (size_t)NIMG * CAP * 8;   // 320 (pad 512)
    size_t off_tok      = off_nnz + 512;                       // 81,920
    size_t off_wt       = off_tok + (size_t)NC * NL * 4;       // 81,920
    size_t off_wavecnt  = off_wt + (size_t)NC * NL * 4;        // 152,000 (+64)
    size_t off_wavemask = off_wavecnt + (size_t)NWAVE * 4 + 64;// 1,216,000
    size_t needed       = off_wavemask + (size_t)NWAVE * 32;
    if (ws_size < needed) return;

    // post-compaction arrays alias the scores region (scores dead after
    // kgather; rewritten from scratch by kscoreh each replay)
    size_t off_sorted = off_scores;                            // 65,536
    size_t off_box4   = off_sorted + (size_t)NIMG * 1024 * 8;  // 131,072
    size_t off_obx4   = off_box4 + (size_t)NIMG * 1024 * 16;   // 131,072
    size_t off_area   = off_obx4 + (size_t)NIMG * 1024 * 16;   // 32,768
    size_t off_lblk   = off_area + (size_t)NIMG * 1024 * 4;    // 32,768

    float*    scores  = (float*)(ws + off_scores);
    unsigned* gh      = (unsigned*)(ws + off_gh);
    unsigned* meta    = (unsigned*)(ws + off_meta);
    unsigned long long* cand = (unsigned long long*)(ws + off_cand);
    unsigned* nnz     = (unsigned*)(ws + off_nnz);
    unsigned* tok     = (unsigned*)(ws + off_tok);
    float*    wt      = (float*)(ws + off_wt);
    unsigned* wavecnt = (unsigned*)(ws + off_wavecnt);
    unsigned long long* wavemask = (unsigned long long*)(ws + off_wavemask);
    unsigned long long* sorted = (unsigned long long*)(ws + off_sorted);
    float4*   box4    = (float4*)(ws + off_box4);
    float4*   obx4    = (float4*)(ws + off_obx4);
    float*    areag   = (float*)(ws + off_area);
    unsigned* lblkeep = (unsigned*)(ws + off_lblk);

    kinit<<<128, 256, 0, stream>>>(pm, nnz, tok, wt, gh);
    kscoreh<<<SBLK32, 512, 0, stream>>>(dp, cent, nnz, tok, wt, scores, gh);
    kfind1<<<NIMG, 256, 0, stream>>>(gh, meta);
    kcountM<<<CBLK, 256, 0, stream>>>((const float4*)scores, meta,
                                      wavecnt, wavemask);
    kgather<<<NIMG, 1024, 0, stream>>>(wavecnt, wavemask, scores, meta,
                                       cand, sorted);
    kdecode<<<(NIMG * TOPK + 255) / 256, 256, 0, stream>>>(sorted, anc, breg,
                                                           box4, obx4, areag, lblkeep);

    float* outBoxes  = (float*)d_out;                       // 8*100*4
    float* outScores = outBoxes + NIMG * NPOST * 4;         // 8*100
    float* outLabels = outScores + NIMG * NPOST;            // 8*100
    knms2<<<NIMG, 1024, 0, stream>>>(sorted, obx4, areag, lblkeep, box4,
                                     outBoxes, outScores, outLabels);
}